// Round 1
// baseline (4476.967 us; speedup 1.0000x reference)
//
#include <hip/hip_runtime.h>
#include <stdint.h>

typedef unsigned int uint;
typedef unsigned short ushort;

// B=2048, W=64, F=128, H=128 fixed by the problem.
#define NB 2048
#define NW 64
#define NF 128
#define NH 128

__device__ __forceinline__ float bfl(uint u){ return __uint_as_float(u << 16); }
__device__ __forceinline__ float bfh(uint u){ return __uint_as_float(u & 0xffff0000u); }
__device__ __forceinline__ ushort f2bf(float f){
  uint u = __float_as_uint(f);
  u += 0x7fffu + ((u >> 16) & 1u);
  return (ushort)(u >> 16);
}
__device__ __forceinline__ float bf2f(ushort s){ return __uint_as_float(((uint)s) << 16); }

// tanh = (e^{2x}-1)/(e^{2x}+1), clamped so e^{2x} can't overflow. ~1e-6 rel err.
__device__ __forceinline__ float fast_tanh(float x){
  x = fminf(8.f, fmaxf(-8.f, x));
  float e = __expf(2.f * x);
  return (e - 1.f) * __builtin_amdgcn_rcpf(e + 1.f);
}
__device__ __forceinline__ float fast_sig(float x){
  x = fminf(30.f, fmaxf(-30.f, x));
  return __builtin_amdgcn_rcpf(1.f + __expf(-x));
}

// ---------------- prep: convert streamed weights to bf16 ----------------
// layout in wbf: enc_Wih[65536] | enc_Whh[65536] | dec_Whh[65536] | l2_W[32768]
__global__ __launch_bounds__(256) void k_prep(const float* __restrict__ wih,
                                              const float* __restrict__ whh,
                                              const float* __restrict__ dwhh,
                                              const float* __restrict__ l2w,
                                              ushort* __restrict__ out){
  int n = 65536*3 + 32768;
  for (int i = blockIdx.x*256 + threadIdx.x; i < n; i += gridDim.x*256){
    float v;
    if (i < 65536)       v = wih[i];
    else if (i < 131072) v = whh[i - 65536];
    else if (i < 196608) v = dwhh[i - 131072];
    else                 v = l2w[i - 196608];
    out[i] = f2bf(v);
  }
}

// ---------------- upre[b][f][w] = sum_j ia_W1[w,j] * X[b,j,f] (j<64) ----------------
__global__ __launch_bounds__(256) void k_upre(const float* __restrict__ X,
                                              const float* __restrict__ iaW1,
                                              ushort* __restrict__ upre){
  __shared__ __align__(16) float sX[NW][NF];   // 32KB  sX[j][f]
  __shared__ __align__(16) float sW[64][65];   // 16.6KB padded, sW[w][j]
  int b = blockIdx.x;
  const float* Xb = X + (size_t)b*NW*NF;
  for (int i = threadIdx.x; i < NW*NF; i += 256) sX[i>>7][i&127] = Xb[i];
  for (int i = threadIdx.x; i < 64*64; i += 256){
    int w = i >> 6, j = i & 63;
    sW[w][j] = iaW1[w*320 + j];
  }
  __syncthreads();
  ushort* outb = upre + (size_t)b*NF*NW;
  for (int k = 0; k < 32; ++k){
    int idx = threadIdx.x + 256*k;   // idx = f*64 + w
    int w = idx & 63, f = idx >> 6;
    float acc = 0.f;
    #pragma unroll 8
    for (int j = 0; j < 64; ++j) acc += sW[w][j] * sX[j][f];
    outb[idx] = f2bf(acc);
  }
}

// ---------------- encoder: 256 blocks x 512 thr, 8 batch rows per block ----------------
__global__ __launch_bounds__(512) void k_enc(
    const float* __restrict__ X, const float* __restrict__ iaW1,
    const float* __restrict__ iab1, const float* __restrict__ iaW2,
    const float* __restrict__ encbih, const float* __restrict__ encbhh,
    const ushort* __restrict__ wih, const ushort* __restrict__ whh,
    const ushort* __restrict__ upre, ushort* __restrict__ Hsb){
  __shared__ __align__(16) ushort sW1hc[64][260];  // [w][j] = bf16(ia_W1[w][64+j]), j<256 (h|c)
  __shared__ __align__(16) float sW2[64];
  __shared__ __align__(16) float h_s[8][128], c_s[8][128];
  __shared__ __align__(16) float uhc[8][64];
  __shared__ __align__(16) float ebuf[8][128];
  __shared__ __align__(16) float xt[8][128];
  __shared__ __align__(16) float gbuf[8][512];
  int tid = threadIdx.x;
  int bbase = blockIdx.x * 8;

  for (int i = tid; i < 64*256; i += 512){
    int w = i >> 8, j = i & 255;
    sW1hc[w][j] = f2bf(iaW1[w*320 + 64 + j]);
  }
  if (tid < 64) sW2[tid] = iaW2[tid];
  for (int i = tid; i < 8*128; i += 512){ h_s[i>>7][i&127] = 0.f; c_s[i>>7][i&127] = 0.f; }
  __syncthreads();

  for (int t = 0; t < NW; ++t){
    // ---- A: uhc[bb][w] = ia_b1[w] + h.Wh + c.Wc ----
    {
      int w = tid & 63, bb = tid >> 6;
      float acc = iab1[w];
      #pragma unroll 4
      for (int j0 = 0; j0 < 128; j0 += 4){
        float4 hv = *(const float4*)&h_s[bb][j0];
        float4 cv = *(const float4*)&c_s[bb][j0];
        uint2 wh = *(const uint2*)&sW1hc[w][j0];
        uint2 wc = *(const uint2*)&sW1hc[w][128 + j0];
        acc += bfl(wh.x)*hv.x + bfh(wh.x)*hv.y + bfl(wh.y)*hv.z + bfh(wh.y)*hv.w
             + bfl(wc.x)*cv.x + bfh(wc.x)*cv.y + bfl(wc.y)*cv.z + bfh(wc.y)*cv.w;
      }
      uhc[bb][w] = acc;
    }
    __syncthreads();
    // ---- B: e[bb][f] = sum_w w2[w]*tanh(upre + uhc) ----
    #pragma unroll
    for (int it = 0; it < 2; ++it){
      int item = tid + it*512;
      int f = item & 127, bb = item >> 7;
      const ushort* up = upre + ((size_t)(bbase + bb)*NF + f)*NW;
      float acc = 0.f;
      #pragma unroll
      for (int w0 = 0; w0 < 64; w0 += 8){
        uint4 uv = *(const uint4*)(up + w0);
        float4 ua = *(const float4*)&uhc[bb][w0];
        float4 ub = *(const float4*)&uhc[bb][w0+4];
        float4 wa = *(const float4*)&sW2[w0];
        float4 wb = *(const float4*)&sW2[w0+4];
        acc += wa.x*fast_tanh(bfl(uv.x)+ua.x);
        acc += wa.y*fast_tanh(bfh(uv.x)+ua.y);
        acc += wa.z*fast_tanh(bfl(uv.y)+ua.z);
        acc += wa.w*fast_tanh(bfh(uv.y)+ua.w);
        acc += wb.x*fast_tanh(bfl(uv.z)+ub.x);
        acc += wb.y*fast_tanh(bfh(uv.z)+ub.y);
        acc += wb.z*fast_tanh(bfl(uv.w)+ub.z);
        acc += wb.w*fast_tanh(bfh(uv.w)+ub.w);
      }
      ebuf[bb][f] = acc;
    }
    __syncthreads();
    // ---- softmax over f (wave r handles bb=r) + xt = alpha * X[:,t,:] ----
    {
      int bb = tid >> 6, l = tid & 63;
      float e0 = ebuf[bb][l], e1 = ebuf[bb][l+64];
      float m = fmaxf(e0, e1);
      #pragma unroll
      for (int off = 32; off; off >>= 1) m = fmaxf(m, __shfl_xor(m, off, 64));
      float x0 = __expf(e0 - m), x1 = __expf(e1 - m);
      float s = x0 + x1;
      #pragma unroll
      for (int off = 32; off; off >>= 1) s += __shfl_xor(s, off, 64);
      float inv = __builtin_amdgcn_rcpf(s);
      const float* Xr = X + (size_t)(bbase + bb)*NW*NF + t*NF;
      xt[bb][l]      = x0*inv*Xr[l];
      xt[bb][l+64]   = x1*inv*Xr[l+64];
    }
    __syncthreads();
    // ---- C: gates. thread j owns rows Wih[j],Whh[j], reused for all 8 bb ----
    {
      int j = tid;
      const ushort* wri = wih + j*128;
      const ushort* wrh = whh + j*128;
      float bias = encbih[j] + encbhh[j];
      float acc[8];
      #pragma unroll
      for (int bb = 0; bb < 8; ++bb) acc[bb] = bias;
      #pragma unroll 4
      for (int f0 = 0; f0 < 128; f0 += 8){
        uint4 wa = *(const uint4*)(wri + f0);
        uint4 wb = *(const uint4*)(wrh + f0);
        float wi0=bfl(wa.x), wi1=bfh(wa.x), wi2=bfl(wa.y), wi3=bfh(wa.y),
              wi4=bfl(wa.z), wi5=bfh(wa.z), wi6=bfl(wa.w), wi7=bfh(wa.w);
        float wh0=bfl(wb.x), wh1=bfh(wb.x), wh2=bfl(wb.y), wh3=bfh(wb.y),
              wh4=bfl(wb.z), wh5=bfh(wb.z), wh6=bfl(wb.w), wh7=bfh(wb.w);
        #pragma unroll
        for (int bb = 0; bb < 8; ++bb){
          float4 xa = *(const float4*)&xt[bb][f0];
          float4 xb = *(const float4*)&xt[bb][f0+4];
          float4 ha = *(const float4*)&h_s[bb][f0];
          float4 hb = *(const float4*)&h_s[bb][f0+4];
          acc[bb] += wi0*xa.x + wi1*xa.y + wi2*xa.z + wi3*xa.w
                   + wi4*xb.x + wi5*xb.y + wi6*xb.z + wi7*xb.w
                   + wh0*ha.x + wh1*ha.y + wh2*ha.z + wh3*ha.w
                   + wh4*hb.x + wh5*hb.y + wh6*hb.z + wh7*hb.w;
        }
      }
      #pragma unroll
      for (int bb = 0; bb < 8; ++bb) gbuf[bb][j] = acc[bb];
    }
    __syncthreads();
    // ---- D: state update + write Hs ----
    #pragma unroll
    for (int it = 0; it < 2; ++it){
      int item = tid + it*512;
      int jj = item & 127, bb = item >> 7;
      float gi = gbuf[bb][jj], gf = gbuf[bb][jj+128];
      float gg = gbuf[bb][jj+256], go = gbuf[bb][jj+384];
      float cn = fast_sig(gf)*c_s[bb][jj] + fast_sig(gi)*fast_tanh(gg);
      float hn = fast_sig(go)*fast_tanh(cn);
      c_s[bb][jj] = cn; h_s[bb][jj] = hn;
      Hsb[((size_t)(bbase + bb)*NW + t)*NH + jj] = f2bf(hn);
    }
    __syncthreads();
  }
}

// ---------------- vpre[b][w][h] = sum_j ta_W1[h,j] * Hs[b][w][j] (j<128) ----------------
__global__ __launch_bounds__(512) void k_vpre(const ushort* __restrict__ Hsb,
                                              const float* __restrict__ taW1,
                                              ushort* __restrict__ vpre){
  __shared__ __align__(16) float sH[NW][NH];    // 32KB  [w][j]
  __shared__ __align__(16) float sT[128][128];  // 64KB  sT[j][h] = taW1[h][j]
  int b = blockIdx.x;
  const ushort* Hb = Hsb + (size_t)b*NW*NH;
  for (int i = threadIdx.x; i < NW*NH; i += 512) sH[i>>7][i&127] = bf2f(Hb[i]);
  for (int i = threadIdx.x; i < 128*128; i += 512){
    int j = i >> 7, h = i & 127;
    sT[j][h] = taW1[h*384 + j];
  }
  __syncthreads();
  ushort* outb = vpre + (size_t)b*NW*NH;
  for (int k = 0; k < 16; ++k){
    int idx = threadIdx.x + 512*k;   // idx = w*128 + h
    int h = idx & 127, w = idx >> 7;
    float acc = 0.f;
    #pragma unroll 8
    for (int j = 0; j < 128; ++j) acc += sT[j][h] * sH[w][j];
    outb[idx] = f2bf(acc);
  }
}

// ---------------- decoder: 256 blocks x 512 thr, 8 batch rows per block ----------------
__global__ __launch_bounds__(512) void k_dec(
    const float* __restrict__ taW1, const float* __restrict__ tab1,
    const float* __restrict__ taW2,
    const float* __restrict__ decWih, const float* __restrict__ decbih,
    const float* __restrict__ decbhh,
    const ushort* __restrict__ dwhh, const ushort* __restrict__ l2w,
    const float* __restrict__ l1W, const float* __restrict__ l1b,
    const float* __restrict__ l2b, const float* __restrict__ l3W,
    const float* __restrict__ l3b,
    const ushort* __restrict__ Hsb, const ushort* __restrict__ vpre,
    float* __restrict__ out){
  __shared__ __align__(16) ushort sTa[256][128]; // 64KB  sTa[j][h] = bf16(taW1[h][128+j])
  __shared__ __align__(16) float sW2[128];
  __shared__ __align__(16) float d_s[8][128], ds_s[8][128];
  __shared__ __align__(16) float vd[8][128];
  __shared__ __align__(16) float lb[8][64];
  __shared__ __align__(16) float ct[8][128];
  __shared__ __align__(16) float gbuf[8][512];
  __shared__ __align__(16) float ob[8][128];
  __shared__ float out_s[8], yt_s[8];
  int tid = threadIdx.x;
  int bbase = blockIdx.x * 8;

  for (int i = tid; i < 256*128; i += 512){
    int j = i >> 7, h = i & 127;
    sTa[j][h] = f2bf(taW1[h*384 + 128 + j]);
  }
  if (tid < 128) sW2[tid] = taW2[tid];
  for (int i = tid; i < 8*128; i += 512){ d_s[i>>7][i&127] = 0.f; ds_s[i>>7][i&127] = 0.f; }
  if (tid < 8) out_s[tid] = 0.f;
  __syncthreads();

  for (int t = 0; t < NW; ++t){
    // ---- A: vd[bb][h] = ta_b1[h] + d.Wd + ds.Wds (thread covers bb and bb+4) ----
    {
      int h = tid & 127, b0 = tid >> 7, b1 = (tid >> 7) + 4;
      float acc0 = tab1[h], acc1 = acc0;
      #pragma unroll 4
      for (int j = 0; j < 128; ++j){
        float wv  = bf2f(sTa[j][h]);
        float wv2 = bf2f(sTa[128 + j][h]);
        float dj0 = d_s[b0][j],  dj1 = d_s[b1][j];
        float sj0 = ds_s[b0][j], sj1 = ds_s[b1][j];
        acc0 += wv*dj0 + wv2*sj0;
        acc1 += wv*dj1 + wv2*sj1;
      }
      vd[b0][h] = acc0; vd[b1][h] = acc1;
    }
    __syncthreads();
    // ---- B: l[bb][w] = sum_h w2[h]*tanh(vpre + vd) ----
    {
      int w = tid & 63, bb = tid >> 6;
      const ushort* vp = vpre + ((size_t)(bbase + bb)*NW + w)*NH;
      float acc = 0.f;
      #pragma unroll
      for (int h0 = 0; h0 < 128; h0 += 8){
        uint4 uv = *(const uint4*)(vp + h0);
        float4 va = *(const float4*)&vd[bb][h0];
        float4 vb = *(const float4*)&vd[bb][h0+4];
        float4 wa = *(const float4*)&sW2[h0];
        float4 wb = *(const float4*)&sW2[h0+4];
        acc += wa.x*fast_tanh(bfl(uv.x)+va.x);
        acc += wa.y*fast_tanh(bfh(uv.x)+va.y);
        acc += wa.z*fast_tanh(bfl(uv.y)+va.z);
        acc += wa.w*fast_tanh(bfh(uv.y)+va.w);
        acc += wb.x*fast_tanh(bfl(uv.z)+vb.x);
        acc += wb.y*fast_tanh(bfh(uv.z)+vb.y);
        acc += wb.z*fast_tanh(bfl(uv.w)+vb.z);
        acc += wb.w*fast_tanh(bfh(uv.w)+vb.w);
      }
      lb[bb][w] = acc;
    }
    __syncthreads();
    // ---- softmax over w (wave r = bb) ----
    {
      int bb = tid >> 6, l = tid & 63;
      float e0 = lb[bb][l];
      float m = e0;
      #pragma unroll
      for (int off = 32; off; off >>= 1) m = fmaxf(m, __shfl_xor(m, off, 64));
      float x0 = __expf(e0 - m);
      float s = x0;
      #pragma unroll
      for (int off = 32; off; off >>= 1) s += __shfl_xor(s, off, 64);
      lb[bb][l] = x0 * __builtin_amdgcn_rcpf(s);
    }
    __syncthreads();
    // ---- C: ct[bb][h] = sum_w beta*Hs ----
    {
      int h2 = tid & 63, bb = tid >> 6;
      int h = h2 * 2;
      const ushort* Hp = Hsb + (size_t)(bbase + bb)*NW*NH + h;
      float a0 = 0.f, a1 = 0.f;
      #pragma unroll 4
      for (int w = 0; w < 64; ++w){
        uint uv = *(const uint*)(Hp + (size_t)w*NH);
        float beta = lb[bb][w];
        a0 += beta * bfl(uv);
        a1 += beta * bfh(uv);
      }
      *(float2*)&ct[bb][h] = make_float2(a0, a1);
    }
    __syncthreads();
    // ---- C2: yt[bb] = l1 . [out, ct] ----
    {
      int bb = tid >> 6, l = tid & 63;
      float p = l1W[1+l]*ct[bb][l] + l1W[1+64+l]*ct[bb][64+l];
      #pragma unroll
      for (int off = 32; off; off >>= 1) p += __shfl_xor(p, off, 64);
      if (l == 0) yt_s[bb] = p + l1W[0]*out_s[bb] + l1b[0];
    }
    __syncthreads();
    // ---- D: decoder LSTM gates ----
    {
      int j = tid;
      const ushort* wr = dwhh + j*128;
      float bias = decbih[j] + decbhh[j];
      float wih0 = decWih[j];
      float acc[8];
      #pragma unroll
      for (int bb = 0; bb < 8; ++bb) acc[bb] = bias + wih0*yt_s[bb];
      #pragma unroll 4
      for (int f0 = 0; f0 < 128; f0 += 8){
        uint4 wv = *(const uint4*)(wr + f0);
        float w0=bfl(wv.x), w1=bfh(wv.x), w2=bfl(wv.y), w3=bfh(wv.y),
              w4=bfl(wv.z), w5=bfh(wv.z), w6=bfl(wv.w), w7=bfh(wv.w);
        #pragma unroll
        for (int bb = 0; bb < 8; ++bb){
          float4 da = *(const float4*)&d_s[bb][f0];
          float4 db = *(const float4*)&d_s[bb][f0+4];
          acc[bb] += w0*da.x + w1*da.y + w2*da.z + w3*da.w
                   + w4*db.x + w5*db.y + w6*db.z + w7*db.w;
        }
      }
      #pragma unroll
      for (int bb = 0; bb < 8; ++bb) gbuf[bb][j] = acc[bb];
    }
    __syncthreads();
    // ---- E: update d, ds ----
    #pragma unroll
    for (int it = 0; it < 2; ++it){
      int item = tid + it*512;
      int jj = item & 127, bb = item >> 7;
      float gi = gbuf[bb][jj], gf = gbuf[bb][jj+128];
      float gg = gbuf[bb][jj+256], go = gbuf[bb][jj+384];
      float cn = fast_sig(gf)*ds_s[bb][jj] + fast_sig(gi)*fast_tanh(gg);
      float hn = fast_sig(go)*fast_tanh(cn);
      ds_s[bb][jj] = cn; d_s[bb][jj] = hn;
    }
    __syncthreads();
    // ---- F: o[bb][h] = l2 . [ct, d_new] (thread covers bb and bb+4) ----
    {
      int h = tid & 127, b0 = tid >> 7, b1 = (tid >> 7) + 4;
      const ushort* wr = l2w + h*256;
      float a0 = l2b[h], a1 = a0;
      #pragma unroll 2
      for (int j0 = 0; j0 < 128; j0 += 8){
        uint4 wv = *(const uint4*)(wr + j0);
        float w0=bfl(wv.x), w1=bfh(wv.x), w2=bfl(wv.y), w3=bfh(wv.y),
              w4=bfl(wv.z), w5=bfh(wv.z), w6=bfl(wv.w), w7=bfh(wv.w);
        float4 xa = *(const float4*)&ct[b0][j0];
        float4 xb = *(const float4*)&ct[b0][j0+4];
        float4 ya = *(const float4*)&ct[b1][j0];
        float4 yb = *(const float4*)&ct[b1][j0+4];
        a0 += w0*xa.x + w1*xa.y + w2*xa.z + w3*xa.w + w4*xb.x + w5*xb.y + w6*xb.z + w7*xb.w;
        a1 += w0*ya.x + w1*ya.y + w2*ya.z + w3*ya.w + w4*yb.x + w5*yb.y + w6*yb.z + w7*yb.w;
      }
      #pragma unroll 2
      for (int j0 = 0; j0 < 128; j0 += 8){
        uint4 wv = *(const uint4*)(wr + 128 + j0);
        float w0=bfl(wv.x), w1=bfh(wv.x), w2=bfl(wv.y), w3=bfh(wv.y),
              w4=bfl(wv.z), w5=bfh(wv.z), w6=bfl(wv.w), w7=bfh(wv.w);
        float4 xa = *(const float4*)&d_s[b0][j0];
        float4 xb = *(const float4*)&d_s[b0][j0+4];
        float4 ya = *(const float4*)&d_s[b1][j0];
        float4 yb = *(const float4*)&d_s[b1][j0+4];
        a0 += w0*xa.x + w1*xa.y + w2*xa.z + w3*xa.w + w4*xb.x + w5*xb.y + w6*xb.z + w7*xb.w;
        a1 += w0*ya.x + w1*ya.y + w2*ya.z + w3*ya.w + w4*yb.x + w5*yb.y + w6*yb.z + w7*yb.w;
      }
      ob[b0][h] = a0; ob[b1][h] = a1;
    }
    __syncthreads();
    // ---- G: out[bb] = sigmoid(l3 . o + b) ----
    {
      int bb = tid >> 6, l = tid & 63;
      float p = l3W[l]*ob[bb][l] + l3W[l+64]*ob[bb][64+l];
      #pragma unroll
      for (int off = 32; off; off >>= 1) p += __shfl_xor(p, off, 64);
      if (l == 0) out_s[bb] = fast_sig(p + l3b[0]);
    }
    __syncthreads();
  }
  if (tid < 8) out[bbase + tid] = out_s[tid];
}

extern "C" void kernel_launch(void* const* d_in, const int* in_sizes, int n_in,
                              void* d_out, int out_size, void* d_ws, size_t ws_size,
                              hipStream_t stream){
  const float* X      = (const float*)d_in[0];
  const float* iaW1   = (const float*)d_in[1];
  const float* iab1   = (const float*)d_in[2];
  const float* iaW2   = (const float*)d_in[3];
  const float* encWih = (const float*)d_in[5];
  const float* encWhh = (const float*)d_in[6];
  const float* encbih = (const float*)d_in[7];
  const float* encbhh = (const float*)d_in[8];
  const float* taW1   = (const float*)d_in[9];
  const float* tab1   = (const float*)d_in[10];
  const float* taW2   = (const float*)d_in[11];
  const float* decWih = (const float*)d_in[13];
  const float* decWhh = (const float*)d_in[14];
  const float* decbih = (const float*)d_in[15];
  const float* decbhh = (const float*)d_in[16];
  const float* l1W    = (const float*)d_in[17];
  const float* l1b    = (const float*)d_in[18];
  const float* l2W    = (const float*)d_in[19];
  const float* l2b    = (const float*)d_in[20];
  const float* l3W    = (const float*)d_in[21];
  const float* l3b    = (const float*)d_in[22];

  char* ws = (char*)d_ws;
  ushort* upre = (ushort*)(ws);                         // 32MB  [B][F][W]
  ushort* Hsb  = (ushort*)(ws + 33554432);              // 32MB  [B][W][H]
  ushort* vpre = (ushort*)(ws + 2*33554432);            // 32MB  [B][W][H]
  ushort* wbf  = (ushort*)(ws + 3*33554432);            // bf16 weights
  ushort* wih  = wbf;
  ushort* whh  = wbf + 65536;
  ushort* dwhh = wbf + 131072;
  ushort* l2wb = wbf + 196608;

  k_prep<<<dim3(256), dim3(256), 0, stream>>>(encWih, encWhh, decWhh, l2W, wbf);
  k_upre<<<dim3(2048), dim3(256), 0, stream>>>(X, iaW1, upre);
  k_enc<<<dim3(256), dim3(512), 0, stream>>>(X, iaW1, iab1, iaW2, encbih, encbhh,
                                             wih, whh, upre, Hsb);
  k_vpre<<<dim3(2048), dim3(512), 0, stream>>>(Hsb, taW1, vpre);
  k_dec<<<dim3(256), dim3(512), 0, stream>>>(taW1, tab1, taW2, decWih, decbih, decbhh,
                                             dwhh, l2wb, l1W, l1b, l2b, l3W, l3b,
                                             Hsb, vpre, (float*)d_out);
}

// Round 2
// 1648.180 us; speedup vs baseline: 2.7163x; 2.7163x over previous
//
#include <hip/hip_runtime.h>
#include <stdint.h>

typedef unsigned int uint;
typedef unsigned short ushort;

#define NB 2048
#define NW 64
#define NF 128
#define NH 128

typedef __attribute__((ext_vector_type(8))) short s8v;
typedef __attribute__((ext_vector_type(4))) float f4v;

#define MFMA16(a, b, c) __builtin_amdgcn_mfma_f32_16x16x32_bf16((a), (b), (c), 0, 0, 0)

__device__ __forceinline__ float bfl(uint u){ return __uint_as_float(u << 16); }
__device__ __forceinline__ float bfh(uint u){ return __uint_as_float(u & 0xffff0000u); }
__device__ __forceinline__ ushort f2bf(float f){
  uint u = __float_as_uint(f);
  u += 0x7fffu + ((u >> 16) & 1u);
  return (ushort)(u >> 16);
}
__device__ __forceinline__ float bf2f(ushort s){ return __uint_as_float(((uint)s) << 16); }

// tanh = 1 - 2/(e^{2x}+1). No clamps: e=inf -> 1, e=0 -> -1.  3 VALU + 2 trans.
__device__ __forceinline__ float fast_tanh(float x){
  float e = __expf(x + x);
  return 1.f - 2.f * __builtin_amdgcn_rcpf(e + 1.f);
}
__device__ __forceinline__ float fast_sig(float x){
  return __builtin_amdgcn_rcpf(1.f + __expf(-x));
}

// pack 8 consecutive f32 -> bf16x8 fragment
__device__ __forceinline__ s8v packW(const float* p){
  s8v r;
  #pragma unroll
  for (int i = 0; i < 8; ++i) r[i] = (short)f2bf(p[i]);
  return r;
}

// acc += sum_i w_i * tanh(u_i + h_i)   (all packed bf16x8 in uint4)
__device__ __forceinline__ float acc8(float acc, uint4 u, uint4 h, uint4 w){
  acc += bfl(w.x)*fast_tanh(bfl(u.x)+bfl(h.x));
  acc += bfh(w.x)*fast_tanh(bfh(u.x)+bfh(h.x));
  acc += bfl(w.y)*fast_tanh(bfl(u.y)+bfl(h.y));
  acc += bfh(w.y)*fast_tanh(bfh(u.y)+bfh(h.y));
  acc += bfl(w.z)*fast_tanh(bfl(u.z)+bfl(h.z));
  acc += bfh(w.z)*fast_tanh(bfh(u.z)+bfh(h.z));
  acc += bfl(w.w)*fast_tanh(bfl(u.w)+bfl(h.w));
  acc += bfh(w.w)*fast_tanh(bfh(u.w)+bfh(h.w));
  return acc;
}

// ---------------- upre[b][f][w] = sum_j ia_W1[w,j] * X[b,j,f] (j<64) ----------------
__global__ __launch_bounds__(256) void k_upre(const float* __restrict__ X,
                                              const float* __restrict__ iaW1,
                                              ushort* __restrict__ upre){
  __shared__ __align__(16) float sX[NW][NF];
  __shared__ __align__(16) float sW[64][65];
  int b = blockIdx.x;
  const float* Xb = X + (size_t)b*NW*NF;
  for (int i = threadIdx.x; i < NW*NF; i += 256) sX[i>>7][i&127] = Xb[i];
  for (int i = threadIdx.x; i < 64*64; i += 256){
    int w = i >> 6, j = i & 63;
    sW[w][j] = iaW1[w*320 + j];
  }
  __syncthreads();
  ushort* outb = upre + (size_t)b*NF*NW;
  for (int k = 0; k < 32; ++k){
    int idx = threadIdx.x + 256*k;   // idx = f*64 + w
    int w = idx & 63, f = idx >> 6;
    float acc = 0.f;
    #pragma unroll 8
    for (int j = 0; j < 64; ++j) acc += sW[w][j] * sX[j][f];
    outb[idx] = f2bf(acc);
  }
}

// ---------------- vpre[b][w][h] = sum_j ta_W1[h,j] * Hs[b][w][j] (j<128) ----------------
__global__ __launch_bounds__(512) void k_vpre(const ushort* __restrict__ Hsb,
                                              const float* __restrict__ taW1,
                                              ushort* __restrict__ vpre){
  __shared__ __align__(16) float sH[NW][NH];
  __shared__ __align__(16) float sT[128][128];
  int b = blockIdx.x;
  const ushort* Hb = Hsb + (size_t)b*NW*NH;
  for (int i = threadIdx.x; i < NW*NH; i += 512) sH[i>>7][i&127] = bf2f(Hb[i]);
  for (int i = threadIdx.x; i < 128*128; i += 512){
    int j = i >> 7, h = i & 127;
    sT[j][h] = taW1[h*384 + j];
  }
  __syncthreads();
  ushort* outb = vpre + (size_t)b*NW*NH;
  for (int k = 0; k < 16; ++k){
    int idx = threadIdx.x + 512*k;   // idx = w*128 + h
    int h = idx & 127, w = idx >> 7;
    float acc = 0.f;
    #pragma unroll 8
    for (int j = 0; j < 128; ++j) acc += sT[j][h] * sH[w][j];
    outb[idx] = f2bf(acc);
  }
}

// =========================== encoder ===========================
// 256 blocks x 512 thr (8 waves), 8 batch rows/block. MFMA for uhc + gates.
__global__ __launch_bounds__(512, 2) void k_enc(
    const float* __restrict__ X, const float* __restrict__ iaW1,
    const float* __restrict__ iab1, const float* __restrict__ iaW2,
    const float* __restrict__ encWih, const float* __restrict__ encWhh,
    const float* __restrict__ encbih, const float* __restrict__ encbhh,
    const ushort* __restrict__ upre, ushort* __restrict__ Hsb){
  __shared__ __align__(16) ushort sUp[65536];     // [bb][f][w] bf16, 16B-slot XOR swizzle
  __shared__ __align__(16) ushort sAB[16*264];    // A-tile: [c|h] then [xt|h], stride 264
  __shared__ __align__(16) float  ebuf[8*128];
  __shared__ __align__(16) ushort uhc_b[8*64];
  __shared__ __align__(16) float  c_s[8*128];
  __shared__ __align__(16) float  bias_s[512];
  __shared__ __align__(16) ushort sW2b[64];

  const int tid = threadIdx.x;
  const int lane = tid & 63, wave = tid >> 6;
  const int bbase = blockIdx.x * 8;

  // ---- init ----
  for (int i = tid; i < 16*264; i += 512) sAB[i] = 0;
  for (int i = tid; i < 1024; i += 512) c_s[i] = 0.f;
  for (int i = tid; i < 512; i += 512) bias_s[i] = encbih[i] + encbhh[i];
  if (tid < 64) sW2b[tid] = f2bf(iaW2[tid]);
  // stage upre slice (t-invariant): 8192 x 16B chunks
  {
    const ushort* up0 = upre + (size_t)bbase*NF*NW;
    #pragma unroll
    for (int k = 0; k < 16; ++k){
      int c = tid + k*512;
      int f = (c >> 3) & 127, s = c & 7;
      uint4 v = *(const uint4*)(up0 + (size_t)c*8);
      *(uint4*)((char*)sUp + ((c>>3))*128 + (((s ^ (f & 7))) << 4)) = v;
    }
  }
  // ---- weight fragments in registers ----
  s8v bwC[4][8];   // gates: B[k][n] = Wc[n][k], n = g*128 + wave*16 + (lane&15)
  #pragma unroll
  for (int g = 0; g < 4; ++g){
    int j = g*128 + wave*16 + (lane & 15);
    #pragma unroll
    for (int kc = 0; kc < 8; ++kc){
      const float* p = (kc < 4) ? (encWih + j*128 + kc*32) : (encWhh + j*128 + (kc-4)*32);
      bwC[g][kc] = packW(p + (lane >> 4)*8);
    }
  }
  s8v bwA[8];      // uhc: A=[c|h]: k<128 -> iaW1 col 192+k (c), k>=128 -> col 64+(k-128) (h)
  if (wave < 4){
    int n = wave*16 + (lane & 15);
    #pragma unroll
    for (int kc = 0; kc < 8; ++kc){
      int col = (kc < 4) ? (192 + kc*32) : (64 + (kc-4)*32);
      bwA[kc] = packW(iaW1 + n*320 + col + (lane >> 4)*8);
    }
  }
  __syncthreads();

  for (int t = 0; t < NW; ++t){
    // ---- A: preread full A-tile ([c|h]); waves 0-3 compute uhc via MFMA ----
    s8v aT[8];
    #pragma unroll
    for (int kc = 0; kc < 8; ++kc)
      aT[kc] = *(const s8v*)((const char*)sAB + (lane&15)*528 + kc*64 + (lane>>4)*16);
    if (wave < 4){
      f4v acc = {0.f, 0.f, 0.f, 0.f};
      #pragma unroll
      for (int kc = 0; kc < 8; ++kc) acc = MFMA16(aT[kc], bwA[kc], acc);
      if (lane < 32){
        int n = wave*16 + (lane & 15);
        float b1v = iab1[n];
        int mb = (lane >> 4)*4;
        #pragma unroll
        for (int j = 0; j < 4; ++j) uhc_b[(mb + j)*64 + n] = f2bf(acc[j] + b1v);
      }
    }
    __syncthreads();  // 1

    // ---- B: e[bb][f] = sum_w W2[w]*tanh(upre + uhc) ----
    {
      int bb = wave;
      const char* r0 = (const char*)sUp + (bb*128 + lane)*128;
      const char* r1 = (const char*)sUp + (bb*128 + 64 + lane)*128;
      int sw0 = (lane & 7) << 4, sw1 = ((lane + 64) & 7) << 4;
      float acc0 = 0.f, acc1 = 0.f;
      #pragma unroll
      for (int s = 0; s < 8; ++s){
        uint4 wv = *(const uint4*)&sW2b[s*8];
        uint4 hv = *(const uint4*)&uhc_b[bb*64 + s*8];
        uint4 u0 = *(const uint4*)(r0 + ((s << 4) ^ sw0));
        uint4 u1 = *(const uint4*)(r1 + ((s << 4) ^ sw1));
        acc0 = acc8(acc0, u0, hv, wv);
        acc1 = acc8(acc1, u1, hv, wv);
      }
      ebuf[bb*128 + lane] = acc0;
      ebuf[bb*128 + 64 + lane] = acc1;
    }
    __syncthreads();  // 2

    // ---- softmax over f (wave bb) + write xt into A-tile cols 0..127 ----
    {
      int bb = wave;
      float e0 = ebuf[bb*128 + lane], e1 = ebuf[bb*128 + 64 + lane];
      float m = fmaxf(e0, e1);
      #pragma unroll
      for (int off = 32; off; off >>= 1) m = fmaxf(m, __shfl_xor(m, off, 64));
      float x0 = __expf(e0 - m), x1 = __expf(e1 - m);
      float s = x0 + x1;
      #pragma unroll
      for (int off = 32; off; off >>= 1) s += __shfl_xor(s, off, 64);
      float inv = __builtin_amdgcn_rcpf(s);
      const float* Xr = X + ((size_t)(bbase + bb)*NW + t)*NF;
      sAB[bb*264 + lane]      = f2bf(x0*inv*Xr[lane]);
      sAB[bb*264 + 64 + lane] = f2bf(x1*inv*Xr[64 + lane]);
    }
    __syncthreads();  // 3

    // ---- C: preread xt fragments ----
    s8v aX[4];
    #pragma unroll
    for (int kc = 0; kc < 4; ++kc)
      aX[kc] = *(const s8v*)((const char*)sAB + (lane&15)*528 + kc*64 + (lane>>4)*16);
    __syncthreads();  // 4

    // ---- C: gates via MFMA ([xt|h]); D: in-wave LSTM update ----
    {
      f4v acc[4];
      #pragma unroll
      for (int g = 0; g < 4; ++g) acc[g] = (f4v){0.f,0.f,0.f,0.f};
      #pragma unroll
      for (int kc = 0; kc < 8; ++kc){
        s8v af = (kc < 4) ? aX[kc] : aT[kc];
        #pragma unroll
        for (int g = 0; g < 4; ++g) acc[g] = MFMA16(af, bwC[g][kc], acc[g]);
      }
      if (lane < 32){
        int n16 = wave*16 + (lane & 15);
        int mb = (lane >> 4)*4;
        float bi = bias_s[n16], bf_ = bias_s[128+n16], bg = bias_s[256+n16], bo = bias_s[384+n16];
        #pragma unroll
        for (int j = 0; j < 4; ++j){
          int m = mb + j;
          float gi = acc[0][j] + bi;
          float gf = acc[1][j] + bf_;
          float gg = acc[2][j] + bg;
          float go = acc[3][j] + bo;
          float cold = c_s[m*128 + n16];
          float cn = fast_sig(gf)*cold + fast_sig(gi)*fast_tanh(gg);
          float hn = fast_sig(go)*fast_tanh(cn);
          c_s[m*128 + n16] = cn;
          sAB[m*264 + n16] = f2bf(cn);          // c part (cols 0..127)
          sAB[m*264 + 128 + n16] = f2bf(hn);    // h part (cols 128..255)
          Hsb[((size_t)(bbase + m)*NW + t)*NH + n16] = f2bf(hn);
        }
      }
    }
    __syncthreads();  // 5
  }
}

// =========================== decoder ===========================
__global__ __launch_bounds__(512, 2) void k_dec(
    const float* __restrict__ taW1, const float* __restrict__ tab1,
    const float* __restrict__ taW2,
    const float* __restrict__ decWih, const float* __restrict__ decWhh,
    const float* __restrict__ decbih, const float* __restrict__ decbhh,
    const float* __restrict__ l1W, const float* __restrict__ l1b,
    const float* __restrict__ l2W, const float* __restrict__ l2b,
    const float* __restrict__ l3W, const float* __restrict__ l3b,
    const ushort* __restrict__ Hsb, const ushort* __restrict__ vpre,
    float* __restrict__ out){
  __shared__ __align__(16) ushort sVp[65536];     // [bb][w][h] bf16, swizzled
  __shared__ __align__(16) ushort sAB[16*264];    // A-tile [d|ds]
  __shared__ __align__(16) ushort sCT[16*136];    // A-tile ct (bf16)
  __shared__ __align__(16) char   scr[4096];      // vd_b (2KB, phases A-B) / o f32 (4KB, F-G)
  __shared__ __align__(16) float  lb[512];        // beta
  __shared__ __align__(16) float  cds_s[1024];
  __shared__ __align__(16) float  bias_s[512];
  __shared__ __align__(16) float  wih_s[512];
  __shared__ __align__(16) ushort sW2b[128];
  __shared__ float yt_s[8], out_s[8];

  const int tid = threadIdx.x;
  const int lane = tid & 63, wave = tid >> 6;
  const int bbase = blockIdx.x * 8;
  ushort* vd_b = (ushort*)scr;
  float*  o_s  = (float*)scr;

  for (int i = tid; i < 16*264; i += 512) sAB[i] = 0;
  for (int i = tid; i < 1024; i += 512) cds_s[i] = 0.f;
  for (int i = tid; i < 512; i += 512){ bias_s[i] = decbih[i] + decbhh[i]; wih_s[i] = decWih[i]; }
  if (tid < 128) sW2b[tid] = f2bf(taW2[tid]);
  if (tid < 8) out_s[tid] = 0.f;
  {
    const ushort* vp0 = vpre + (size_t)bbase*NW*NH;
    #pragma unroll
    for (int k = 0; k < 16; ++k){
      int c = tid + k*512;
      int w = (c >> 4) & 63, s = c & 15;
      uint4 v = *(const uint4*)(vp0 + (size_t)c*8);
      *(uint4*)((char*)sVp + (c >> 4)*256 + ((s ^ (w & 15)) << 4)) = v;
    }
  }
  // weight fragments
  s8v bwA[8];     // vd: B[k][h] = taW1[h][128+k]
  {
    int n = wave*16 + (lane & 15);
    #pragma unroll
    for (int kc = 0; kc < 8; ++kc)
      bwA[kc] = packW(taW1 + n*384 + 128 + kc*32 + (lane >> 4)*8);
  }
  s8v bwD[4][4];  // gates: B[k][j] = decWhh[j][k]
  #pragma unroll
  for (int g = 0; g < 4; ++g){
    int j = g*128 + wave*16 + (lane & 15);
    #pragma unroll
    for (int kc = 0; kc < 4; ++kc)
      bwD[g][kc] = packW(decWhh + j*128 + kc*32 + (lane >> 4)*8);
  }
  s8v bwF[8];     // o: B[k][h] = l2W[h][k]  (k<128 ct, k>=128 d)
  {
    int n = wave*16 + (lane & 15);
    #pragma unroll
    for (int kc = 0; kc < 8; ++kc)
      bwF[kc] = packW(l2W + n*256 + kc*32 + (lane >> 4)*8);
  }
  __syncthreads();

  for (int t = 0; t < NW; ++t){
    // ---- A: vd = [d|ds] @ taW1_part^T + tab1, via MFMA ----
    s8v aT[8];
    #pragma unroll
    for (int kc = 0; kc < 8; ++kc)
      aT[kc] = *(const s8v*)((const char*)sAB + (lane&15)*528 + kc*64 + (lane>>4)*16);
    {
      f4v acc = {0.f,0.f,0.f,0.f};
      #pragma unroll
      for (int kc = 0; kc < 8; ++kc) acc = MFMA16(aT[kc], bwA[kc], acc);
      if (lane < 32){
        int n = wave*16 + (lane & 15);
        float tb = tab1[n];
        int mb = (lane >> 4)*4;
        #pragma unroll
        for (int j = 0; j < 4; ++j) vd_b[(mb + j)*128 + n] = f2bf(acc[j] + tb);
      }
    }
    __syncthreads();  // 1

    // ---- B: l[bb][w] = sum_h W2[h]*tanh(vpre + vd); fused softmax over w ----
    {
      int bb = wave, w = lane;
      const char* rv = (const char*)sVp + (bb*64 + w)*256;
      int sw = (w & 15) << 4;
      float a = 0.f;
      #pragma unroll
      for (int s = 0; s < 16; ++s){
        uint4 wv = *(const uint4*)&sW2b[s*8];
        uint4 dv = *(const uint4*)&vd_b[bb*128 + s*8];
        uint4 u  = *(const uint4*)(rv + ((s << 4) ^ sw));
        a = acc8(a, u, dv, wv);
      }
      float m = a;
      #pragma unroll
      for (int off = 32; off; off >>= 1) m = fmaxf(m, __shfl_xor(m, off, 64));
      float x = __expf(a - m);
      float s = x;
      #pragma unroll
      for (int off = 32; off; off >>= 1) s += __shfl_xor(s, off, 64);
      lb[bb*64 + w] = x * __builtin_amdgcn_rcpf(s);
    }
    __syncthreads();  // 2

    // ---- C: ct = sum_w beta*Hs (global, L2-hot); fused yt reduce ----
    {
      int bb = wave, h2 = lane;
      const ushort* Hp = Hsb + (size_t)(bbase + bb)*NW*NH + 2*h2;
      float a0 = 0.f, a1 = 0.f;
      #pragma unroll 8
      for (int w = 0; w < 64; ++w){
        uint uv = *(const uint*)(Hp + w*NH);
        float beta = lb[bb*64 + w];
        a0 += beta * bfl(uv);
        a1 += beta * bfh(uv);
      }
      *(uint*)((char*)sCT + bb*272 + h2*4) = (uint)f2bf(a0) | ((uint)f2bf(a1) << 16);
      float p = l1W[1 + 2*h2]*a0 + l1W[2 + 2*h2]*a1;
      #pragma unroll
      for (int off = 32; off; off >>= 1) p += __shfl_xor(p, off, 64);
      if (lane == 0) yt_s[bb] = p + l1W[0]*out_s[bb] + l1b[0];
    }
    __syncthreads();  // 3

    // ---- D: gates via MFMA (reuse aT[0..3] = old d); E: in-wave update ----
    {
      f4v g4[4];
      #pragma unroll
      for (int g = 0; g < 4; ++g) g4[g] = (f4v){0.f,0.f,0.f,0.f};
      #pragma unroll
      for (int kc = 0; kc < 4; ++kc){
        #pragma unroll
        for (int g = 0; g < 4; ++g) g4[g] = MFMA16(aT[kc], bwD[g][kc], g4[g]);
      }
      if (lane < 32){
        int n16 = wave*16 + (lane & 15);
        int mb = (lane >> 4)*4;
        float bi = bias_s[n16], bf_ = bias_s[128+n16], bg = bias_s[256+n16], bo = bias_s[384+n16];
        float wi = wih_s[n16], wf = wih_s[128+n16], wg = wih_s[256+n16], wo = wih_s[384+n16];
        #pragma unroll
        for (int j = 0; j < 4; ++j){
          int m = mb + j;
          float yt = yt_s[m];
          float gi = g4[0][j] + bi + wi*yt;
          float gf = g4[1][j] + bf_ + wf*yt;
          float gg = g4[2][j] + bg + wg*yt;
          float go = g4[3][j] + bo + wo*yt;
          float cold = cds_s[m*128 + n16];
          float cn = fast_sig(gf)*cold + fast_sig(gi)*fast_tanh(gg);
          float hn = fast_sig(go)*fast_tanh(cn);
          cds_s[m*128 + n16] = cn;
          sAB[m*264 + n16] = f2bf(hn);         // d (cols 0..127)
          sAB[m*264 + 128 + n16] = f2bf(cn);   // ds (cols 128..255)
        }
      }
    }
    __syncthreads();  // 4

    // ---- F: o = [ct|d_new] @ l2W^T + l2b, via MFMA ----
    {
      f4v of = {0.f,0.f,0.f,0.f};
      #pragma unroll
      for (int kc = 0; kc < 4; ++kc){
        s8v af = *(const s8v*)((const char*)sCT + (lane&15)*272 + kc*64 + (lane>>4)*16);
        of = MFMA16(af, bwF[kc], of);
      }
      #pragma unroll
      for (int kc = 4; kc < 8; ++kc){
        s8v af = *(const s8v*)((const char*)sAB + (lane&15)*528 + (kc-4)*64 + (lane>>4)*16);
        of = MFMA16(af, bwF[kc], of);
      }
      if (lane < 32){
        int n16 = wave*16 + (lane & 15);
        int mb = (lane >> 4)*4;
        float l2bv = l2b[n16];
        #pragma unroll
        for (int j = 0; j < 4; ++j) o_s[(mb + j)*128 + n16] = of[j] + l2bv;
      }
    }
    __syncthreads();  // 5

    // ---- G: out = sigmoid(l3 . o + l3b) ----
    {
      int bb = wave, h2 = lane;
      float o0 = o_s[bb*128 + 2*h2], o1 = o_s[bb*128 + 2*h2 + 1];
      float p = l3W[2*h2]*o0 + l3W[2*h2 + 1]*o1;
      #pragma unroll
      for (int off = 32; off; off >>= 1) p += __shfl_xor(p, off, 64);
      if (lane == 0) out_s[bb] = fast_sig(p + l3b[0]);
    }
    __syncthreads();  // 6
  }
  if (tid < 8) out[bbase + tid] = out_s[tid];
}

extern "C" void kernel_launch(void* const* d_in, const int* in_sizes, int n_in,
                              void* d_out, int out_size, void* d_ws, size_t ws_size,
                              hipStream_t stream){
  const float* X      = (const float*)d_in[0];
  const float* iaW1   = (const float*)d_in[1];
  const float* iab1   = (const float*)d_in[2];
  const float* iaW2   = (const float*)d_in[3];
  const float* encWih = (const float*)d_in[5];
  const float* encWhh = (const float*)d_in[6];
  const float* encbih = (const float*)d_in[7];
  const float* encbhh = (const float*)d_in[8];
  const float* taW1   = (const float*)d_in[9];
  const float* tab1   = (const float*)d_in[10];
  const float* taW2   = (const float*)d_in[11];
  const float* decWih = (const float*)d_in[13];
  const float* decWhh = (const float*)d_in[14];
  const float* decbih = (const float*)d_in[15];
  const float* decbhh = (const float*)d_in[16];
  const float* l1W    = (const float*)d_in[17];
  const float* l1b    = (const float*)d_in[18];
  const float* l2W    = (const float*)d_in[19];
  const float* l2b    = (const float*)d_in[20];
  const float* l3W    = (const float*)d_in[21];
  const float* l3b    = (const float*)d_in[22];

  char* ws = (char*)d_ws;
  ushort* upre = (ushort*)(ws);                // 32MB [B][F][W]
  ushort* Hsb  = (ushort*)(ws + 33554432);     // 32MB [B][W][H]
  ushort* vpre = (ushort*)(ws + 2*33554432);   // 32MB [B][W][H]

  k_upre<<<dim3(2048), dim3(256), 0, stream>>>(X, iaW1, upre);
  k_enc<<<dim3(256), dim3(512), 0, stream>>>(X, iaW1, iab1, iaW2,
                                             encWih, encWhh, encbih, encbhh,
                                             upre, Hsb);
  k_vpre<<<dim3(2048), dim3(512), 0, stream>>>(Hsb, taW1, vpre);
  k_dec<<<dim3(256), dim3(512), 0, stream>>>(taW1, tab1, taW2,
                                             decWih, decWhh, decbih, decbhh,
                                             l1W, l1b, l2W, l2b, l3W, l3b,
                                             Hsb, vpre, (float*)d_out);
}

// Round 4
// 1608.307 us; speedup vs baseline: 2.7837x; 1.0248x over previous
//
#include <hip/hip_runtime.h>
#include <hip/hip_fp16.h>
#include <stdint.h>

typedef unsigned int uint;
typedef unsigned short ushort;

#define NB 2048
#define NW 64
#define NF 128
#define NH 128

typedef __attribute__((ext_vector_type(8))) short s8v;
typedef __attribute__((ext_vector_type(8))) _Float16 h8v;
typedef __attribute__((ext_vector_type(4))) float f4v;

#define MFMA16(a, b, c) __builtin_amdgcn_mfma_f32_16x16x32_bf16((a), (b), (c), 0, 0, 0)
#define MFMAH(a, b, c)  __builtin_amdgcn_mfma_f32_16x16x32_f16((a), (b), (c), 0, 0, 0)

union H8 { h8v v; __half2 h2[4]; uint4 u4; ushort us[8]; };

__device__ __forceinline__ float bfl(uint u){ return __uint_as_float(u << 16); }
__device__ __forceinline__ float bfh(uint u){ return __uint_as_float(u & 0xffff0000u); }
__device__ __forceinline__ ushort f2bf(float f){
  uint u = __float_as_uint(f);
  u += 0x7fffu + ((u >> 16) & 1u);
  return (ushort)(u >> 16);
}
__device__ __forceinline__ float bf2f(ushort s){ return __uint_as_float(((uint)s) << 16); }

__device__ __forceinline__ float fast_tanh(float x){
  float e = __expf(x + x);
  return 1.f - 2.f * __builtin_amdgcn_rcpf(e + 1.f);
}
__device__ __forceinline__ float fast_sig(float x){
  return __builtin_amdgcn_rcpf(1.f + __expf(-x));
}
__device__ __forceinline__ ushort expo_h(float x){  // f16 bits of exp(2x)
  return __half_as_ushort(__float2half(__expf(x + x)));
}

// pack 8 consecutive f32 -> bf16x8 fragment
__device__ __forceinline__ s8v packW(const float* p){
  s8v r;
  #pragma unroll
  for (int i = 0; i < 8; ++i) r[i] = (short)f2bf(p[i]);
  return r;
}

// ---------------- E_enc[b][f][w] = exp(2 * sum_j ia_W1[w,j]*X[b,j,f]) (f16) ----------------
__global__ __launch_bounds__(256) void k_upre(const float* __restrict__ X,
                                              const float* __restrict__ iaW1,
                                              ushort* __restrict__ Eenc){
  __shared__ __align__(16) float sX[NW*NF];
  __shared__ __align__(16) float sW[64*65];
  int b = blockIdx.x;
  const float* Xb = X + (size_t)b*NW*NF;
  for (int i = threadIdx.x; i < NW*NF; i += 256) sX[i] = Xb[i];
  for (int i = threadIdx.x; i < 64*64; i += 256){
    int w = i >> 6, j = i & 63;
    sW[w*65 + j] = iaW1[w*320 + j];
  }
  __syncthreads();
  ushort* outb = Eenc + (size_t)b*NF*NW;
  for (int k = 0; k < 32; ++k){
    int idx = threadIdx.x + 256*k;   // idx = f*64 + w
    int w = idx & 63, f = idx >> 6;
    float acc = 0.f;
    #pragma unroll 8
    for (int j = 0; j < 64; ++j) acc += sW[w*65 + j] * sX[j*128 + f];
    outb[idx] = expo_h(acc);
  }
}

// ------- E_dec[b][w][h] = exp(2*vpre) (f16), HsT[b][h][w] = Hs^T (bf16) -------
__global__ __launch_bounds__(512) void k_vpre(const ushort* __restrict__ Hsb,
                                              const float* __restrict__ taW1,
                                              ushort* __restrict__ Edec,
                                              ushort* __restrict__ HsT){
  __shared__ __align__(16) float sH[64*129];
  __shared__ __align__(16) float sT[128*128];
  int b = blockIdx.x;
  const ushort* Hb = Hsb + (size_t)b*NW*NH;
  for (int i = threadIdx.x; i < NW*NH; i += 512) sH[(i>>7)*129 + (i&127)] = bf2f(Hb[i]);
  for (int i = threadIdx.x; i < 128*128; i += 512){
    int j = i >> 7, h = i & 127;
    sT[j*128 + h] = taW1[h*384 + j];
  }
  __syncthreads();
  ushort* ho = HsT + (size_t)b*NH*NW;
  #pragma unroll
  for (int k = 0; k < 16; ++k){
    int i2 = threadIdx.x + 512*k;    // i2 = h*64 + w
    int h = i2 >> 6, w = i2 & 63;
    ho[i2] = f2bf(sH[w*129 + h]);
  }
  ushort* outb = Edec + (size_t)b*NW*NH;
  for (int k = 0; k < 16; ++k){
    int idx = threadIdx.x + 512*k;   // idx = w*128 + h
    int h = idx & 127, w = idx >> 7;
    float acc = 0.f;
    #pragma unroll 8
    for (int j = 0; j < 128; ++j) acc += sT[j*128 + h] * sH[w*129 + j];
    outb[idx] = expo_h(acc);
  }
}

// =========================== encoder ===========================
__global__ __launch_bounds__(512, 2) void k_enc(
    const float* __restrict__ X, const float* __restrict__ iaW1,
    const float* __restrict__ iab1, const float* __restrict__ iaW2,
    const float* __restrict__ encWih, const float* __restrict__ encWhh,
    const float* __restrict__ encbih, const float* __restrict__ encbhh,
    const ushort* __restrict__ Eenc, ushort* __restrict__ Hsb){
  __shared__ __align__(16) ushort sUp[65536];    // E_enc slice [bb][f][w] f16, slot-XOR
  __shared__ __align__(16) ushort sAB[16*264];   // A-tile [c|h] / [xt|h] bf16
  __shared__ __align__(16) ushort uhc_h[8*64];   // exp(2*uhc) f16
  __shared__ __align__(16) float  c_s[8*128];
  __shared__ __align__(16) float  bias_s[512];

  const int tid = threadIdx.x, lane = tid & 63, wave = tid >> 6, g = lane >> 4;
  const int bbase = blockIdx.x * 8;

  for (int i = tid; i < 16*264; i += 512) sAB[i] = 0;
  for (int i = tid; i < 1024; i += 512) c_s[i] = 0.f;
  bias_s[tid] = encbih[tid] + encbhh[tid];
  {
    const ushort* up0 = Eenc + (size_t)bbase*NF*NW;
    #pragma unroll
    for (int k = 0; k < 16; ++k){
      int c = tid + k*512;
      int f = (c >> 3) & 127, s = c & 7;
      uint4 v = *(const uint4*)(up0 + (size_t)c*8);
      *(uint4*)((char*)sUp + (c>>3)*128 + ((s ^ (f & 7)) << 4)) = v;
    }
  }
  // weight fragments
  s8v bwC[4][8];
  #pragma unroll
  for (int gg = 0; gg < 4; ++gg){
    int j = gg*128 + wave*16 + (lane & 15);
    #pragma unroll
    for (int kc = 0; kc < 8; ++kc){
      const float* p = (kc < 4) ? (encWih + j*128 + kc*32) : (encWhh + j*128 + (kc-4)*32);
      bwC[gg][kc] = packW(p + g*8);
    }
  }
  s8v bwA[8];
  if (wave < 4){
    int n = wave*16 + (lane & 15);
    #pragma unroll
    for (int kc = 0; kc < 8; ++kc){
      int col = (kc < 4) ? (192 + kc*32) : (64 + (kc-4)*32);
      bwA[kc] = packW(iaW1 + n*320 + col + g*8);
    }
  }
  H8 w2f[2];
  #pragma unroll
  for (int kb = 0; kb < 2; ++kb)
    #pragma unroll
    for (int i = 0; i < 8; ++i)
      w2f[kb].v[i] = (_Float16)iaW2[kb*32 + g*8 + i];
  __syncthreads();

  for (int t = 0; t < NW; ++t){
    // ---- A: read [c|h]; waves 0-3: uhc via MFMA, store exp(2*uhc) f16 ----
    s8v aT[8];
    #pragma unroll
    for (int kc = 0; kc < 8; ++kc)
      aT[kc] = *(const s8v*)((const char*)sAB + (lane&15)*528 + kc*64 + g*16);
    if (wave < 4){
      f4v acc = {0.f,0.f,0.f,0.f};
      #pragma unroll
      for (int kc = 0; kc < 8; ++kc) acc = MFMA16(aT[kc], bwA[kc], acc);
      if (lane < 32){
        int n = wave*16 + (lane & 15);
        float b1v = iab1[n];
        int mb = g*4;
        #pragma unroll
        for (int j = 0; j < 4; ++j) uhc_h[(mb+j)*64 + n] = expo_h(acc[j] + b1v);
      }
    }
    __syncthreads();  // 1

    // ---- B: M[f] = sum_w W2[w]*r, r = 1/(E*s+1); softmax in-register; write xt ----
    {
      int bb = wave;
      const char* Eb = (const char*)sUp + bb*16384;
      H8 sv[2];
      #pragma unroll
      for (int kb = 0; kb < 2; ++kb)
        sv[kb].u4 = *(const uint4*)((const char*)uhc_h + bb*128 + kb*64 + g*16);
      __half2 one2 = __float2half2_rn(1.f);
      f4v Mc[8];
      #pragma unroll
      for (int ft = 0; ft < 8; ++ft){
        int f = ft*16 + (lane & 15);
        const char* rowp = Eb + f*128;
        f4v acc = {0.f,0.f,0.f,0.f};
        #pragma unroll
        for (int kb = 0; kb < 2; ++kb){
          H8 e, a;
          e.v = *(const h8v*)(rowp + (((kb*4 + g) ^ (f & 7)) << 4));
          #pragma unroll
          for (int q = 0; q < 4; ++q) a.h2[q] = h2rcp(__hfma2(e.h2[q], sv[kb].h2[q], one2));
          acc = MFMAH(a.v, w2f[kb].v, acc);
        }
        Mc[ft] = acc;
      }
      float mn = Mc[0][0];
      #pragma unroll
      for (int ft = 0; ft < 8; ++ft)
        #pragma unroll
        for (int r = 0; r < 4; ++r) mn = fminf(mn, Mc[ft][r]);
      mn = fminf(mn, __shfl_xor(mn, 16, 64));
      mn = fminf(mn, __shfl_xor(mn, 32, 64));
      float xs[8][4]; float ssum = 0.f;
      #pragma unroll
      for (int ft = 0; ft < 8; ++ft)
        #pragma unroll
        for (int r = 0; r < 4; ++r){ float x = __expf(2.f*(mn - Mc[ft][r])); xs[ft][r] = x; ssum += x; }
      ssum += __shfl_xor(ssum, 16, 64);
      ssum += __shfl_xor(ssum, 32, 64);
      float inv = __builtin_amdgcn_rcpf(ssum);
      if ((lane & 15) == 0){
        const float* Xr = X + ((size_t)(bbase + bb)*NW + t)*NF;
        #pragma unroll
        for (int ft = 0; ft < 8; ++ft){
          int f0 = ft*16 + g*4;
          float4 Xv = *(const float4*)(Xr + f0);
          uint lo = (uint)f2bf(xs[ft][0]*inv*Xv.x) | ((uint)f2bf(xs[ft][1]*inv*Xv.y) << 16);
          uint hi = (uint)f2bf(xs[ft][2]*inv*Xv.z) | ((uint)f2bf(xs[ft][3]*inv*Xv.w) << 16);
          *(uint2*)((char*)sAB + bb*528 + f0*2) = make_uint2(lo, hi);
        }
      }
    }
    __syncthreads();  // 2

    // ---- C: read xt frags ----
    s8v aX[4];
    #pragma unroll
    for (int kc = 0; kc < 4; ++kc)
      aX[kc] = *(const s8v*)((const char*)sAB + (lane&15)*528 + kc*64 + g*16);
    __syncthreads();  // 3

    // ---- gates via MFMA; in-wave LSTM update ----
    {
      f4v acc[4];
      #pragma unroll
      for (int gg = 0; gg < 4; ++gg) acc[gg] = (f4v){0.f,0.f,0.f,0.f};
      #pragma unroll
      for (int kc = 0; kc < 8; ++kc){
        s8v af = (kc < 4) ? aX[kc] : aT[kc];
        #pragma unroll
        for (int gg = 0; gg < 4; ++gg) acc[gg] = MFMA16(af, bwC[gg][kc], acc[gg]);
      }
      if (lane < 32){
        int n16 = wave*16 + (lane & 15);
        int mb = g*4;
        float bi = bias_s[n16], bf_ = bias_s[128+n16], bg = bias_s[256+n16], bo = bias_s[384+n16];
        #pragma unroll
        for (int j = 0; j < 4; ++j){
          int m = mb + j;
          float gi = acc[0][j] + bi;
          float gf = acc[1][j] + bf_;
          float gg2 = acc[2][j] + bg;
          float go = acc[3][j] + bo;
          float cold = c_s[m*128 + n16];
          float cn = fast_sig(gf)*cold + fast_sig(gi)*fast_tanh(gg2);
          float hn = fast_sig(go)*fast_tanh(cn);
          c_s[m*128 + n16] = cn;
          sAB[m*264 + n16] = f2bf(cn);
          sAB[m*264 + 128 + n16] = f2bf(hn);
          Hsb[((size_t)(bbase + m)*NW + t)*NH + n16] = f2bf(hn);
        }
      }
    }
    __syncthreads();  // 4
  }
}

// =========================== decoder ===========================
__global__ __launch_bounds__(512, 2) void k_dec(
    const float* __restrict__ taW1, const float* __restrict__ tab1,
    const float* __restrict__ taW2,
    const float* __restrict__ decWih, const float* __restrict__ decWhh,
    const float* __restrict__ decbih, const float* __restrict__ decbhh,
    const float* __restrict__ l1W, const float* __restrict__ l1b,
    const float* __restrict__ l2W, const float* __restrict__ l2b,
    const float* __restrict__ l3W, const float* __restrict__ l3b,
    const ushort* __restrict__ Edec, const ushort* __restrict__ HsT,
    float* __restrict__ out){
  __shared__ __align__(16) ushort sVp[65536];    // E_dec slice [bb][w][h] f16, slot-XOR
  __shared__ __align__(16) ushort sAB[16*264];   // [d|ds] bf16
  __shared__ __align__(16) ushort sCT[16*136];   // ct bf16
  __shared__ __align__(16) ushort vd_h[8*128];   // exp(2*vd) f16
  __shared__ __align__(16) ushort lb_bf[8*64];   // beta bf16
  __shared__ __align__(16) float  o_s[8*128];
  __shared__ __align__(16) float  cds_s[1024];
  __shared__ __align__(16) float  bias_s[512];
  __shared__ __align__(16) float  wih_s[512];
  __shared__ float yt_s[8], out_s[8];

  const int tid = threadIdx.x, lane = tid & 63, wave = tid >> 6, g = lane >> 4;
  const int bbase = blockIdx.x * 8;

  for (int i = tid; i < 16*264; i += 512) sAB[i] = 0;
  for (int i = tid; i < 16*136; i += 512) sCT[i] = 0;
  for (int i = tid; i < 1024; i += 512) cds_s[i] = 0.f;
  bias_s[tid] = decbih[tid] + decbhh[tid];
  wih_s[tid] = decWih[tid];
  if (tid < 8) out_s[tid] = 0.f;
  {
    const ushort* vp0 = Edec + (size_t)bbase*NW*NH;
    #pragma unroll
    for (int k = 0; k < 16; ++k){
      int c = tid + k*512;
      int w = (c >> 4) & 63, s = c & 15;
      uint4 v = *(const uint4*)(vp0 + (size_t)c*8);
      *(uint4*)((char*)sVp + (c >> 4)*256 + ((s ^ (w & 15)) << 4)) = v;
    }
  }
  // weight fragments
  s8v bwA[8];     // vd: B[k][h] = taW1[h][128+k]
  {
    int n = wave*16 + (lane & 15);
    #pragma unroll
    for (int kc = 0; kc < 8; ++kc)
      bwA[kc] = packW(taW1 + n*384 + 128 + kc*32 + g*8);
  }
  s8v bwD[4][4];  // gates: B[k][j] = decWhh[j][k]
  #pragma unroll
  for (int gg = 0; gg < 4; ++gg){
    int j = gg*128 + wave*16 + (lane & 15);
    #pragma unroll
    for (int kc = 0; kc < 4; ++kc)
      bwD[gg][kc] = packW(decWhh + j*128 + kc*32 + g*8);
  }
  s8v bwF[8];     // o: B[k][h] = l2W[h][k]
  {
    int n = wave*16 + (lane & 15);
    #pragma unroll
    for (int kc = 0; kc < 8; ++kc)
      bwF[kc] = packW(l2W + n*256 + kc*32 + g*8);
  }
  H8 w2df[4];
  #pragma unroll
  for (int kb = 0; kb < 4; ++kb)
    #pragma unroll
    for (int i = 0; i < 8; ++i)
      w2df[kb].v[i] = (_Float16)taW2[kb*32 + g*8 + i];
  __syncthreads();

  for (int t = 0; t < NW; ++t){
    // ---- A: vd via MFMA from [d|ds]; store exp(2*vd) f16 ----
    s8v aT[8];
    #pragma unroll
    for (int kc = 0; kc < 8; ++kc)
      aT[kc] = *(const s8v*)((const char*)sAB + (lane&15)*528 + kc*64 + g*16);
    {
      f4v acc = {0.f,0.f,0.f,0.f};
      #pragma unroll
      for (int kc = 0; kc < 8; ++kc) acc = MFMA16(aT[kc], bwA[kc], acc);
      if (lane < 32){
        int n = wave*16 + (lane & 15);
        float tb = tab1[n];
        int mb = g*4;
        #pragma unroll
        for (int j = 0; j < 4; ++j) vd_h[(mb+j)*128 + n] = expo_h(acc[j] + tb);
      }
    }
    __syncthreads();  // 1

    // ---- B: M[w] = sum_h W2[h]*r; softmax in-register; write beta bf16 ----
    {
      int bb = wave;
      const char* Eb = (const char*)sVp + bb*16384;   // 64 rows x 256B per batch
      H8 sv[4];
      #pragma unroll
      for (int kb = 0; kb < 4; ++kb)
        sv[kb].u4 = *(const uint4*)((const char*)vd_h + bb*256 + kb*64 + g*16);
      __half2 one2 = __float2half2_rn(1.f);
      f4v Mc[4];
      #pragma unroll
      for (int wt = 0; wt < 4; ++wt){
        int w = wt*16 + (lane & 15);
        const char* rowp = Eb + w*256;
        f4v acc = {0.f,0.f,0.f,0.f};
        #pragma unroll
        for (int kb = 0; kb < 4; ++kb){
          H8 e, a;
          e.v = *(const h8v*)(rowp + (((kb*4 + g) ^ (w & 15)) << 4));
          #pragma unroll
          for (int q = 0; q < 4; ++q) a.h2[q] = h2rcp(__hfma2(e.h2[q], sv[kb].h2[q], one2));
          acc = MFMAH(a.v, w2df[kb].v, acc);
        }
        Mc[wt] = acc;
      }
      float mn = Mc[0][0];
      #pragma unroll
      for (int wt = 0; wt < 4; ++wt)
        #pragma unroll
        for (int r = 0; r < 4; ++r) mn = fminf(mn, Mc[wt][r]);
      mn = fminf(mn, __shfl_xor(mn, 16, 64));
      mn = fminf(mn, __shfl_xor(mn, 32, 64));
      float xs[4][4]; float ssum = 0.f;
      #pragma unroll
      for (int wt = 0; wt < 4; ++wt)
        #pragma unroll
        for (int r = 0; r < 4; ++r){ float x = __expf(2.f*(mn - Mc[wt][r])); xs[wt][r] = x; ssum += x; }
      ssum += __shfl_xor(ssum, 16, 64);
      ssum += __shfl_xor(ssum, 32, 64);
      float inv = __builtin_amdgcn_rcpf(ssum);
      if ((lane & 15) == 0){
        #pragma unroll
        for (int wt = 0; wt < 4; ++wt){
          int w0 = wt*16 + g*4;
          uint lo = (uint)f2bf(xs[wt][0]*inv) | ((uint)f2bf(xs[wt][1]*inv) << 16);
          uint hi = (uint)f2bf(xs[wt][2]*inv) | ((uint)f2bf(xs[wt][3]*inv) << 16);
          *(uint2*)((char*)lb_bf + wave*128 + w0*2) = make_uint2(lo, hi);
        }
      }
    }
    __syncthreads();  // 2

    // ---- C: ct = beta^T * Hs via MFMA (B from HsT, L2-hot); yt reduce ----
    {
      int bb = wave;
      s8v ba[2];
      #pragma unroll
      for (int kb = 0; kb < 2; ++kb)
        ba[kb] = *(const s8v*)((const char*)lb_bf + bb*128 + kb*64 + g*16);
      const ushort* hb = HsT + (size_t)(bbase + bb)*NH*NW;
      float p = 0.f;
      #pragma unroll
      for (int ht = 0; ht < 8; ++ht){
        int h = ht*16 + (lane & 15);
        f4v acc = {0.f,0.f,0.f,0.f};
        #pragma unroll
        for (int kb = 0; kb < 2; ++kb){
          s8v bf = *(const s8v*)(hb + h*64 + kb*32 + g*8);
          acc = MFMA16(ba[kb], bf, acc);
        }
        float ctv = acc[0];
        if (lane < 16) sCT[bb*136 + h] = f2bf(ctv);
        p += l1W[1 + h] * ctv;
      }
      p += __shfl_xor(p, 1, 64);
      p += __shfl_xor(p, 2, 64);
      p += __shfl_xor(p, 4, 64);
      p += __shfl_xor(p, 8, 64);
      if (lane == 0) yt_s[bb] = p + l1W[0]*out_s[bb] + l1b[0];
    }
    __syncthreads();  // 3

    // ---- D: decoder LSTM gates via MFMA + in-wave update ----
    {
      f4v g4[4];
      #pragma unroll
      for (int gg = 0; gg < 4; ++gg) g4[gg] = (f4v){0.f,0.f,0.f,0.f};
      #pragma unroll
      for (int kc = 0; kc < 4; ++kc){
        #pragma unroll
        for (int gg = 0; gg < 4; ++gg) g4[gg] = MFMA16(aT[kc], bwD[gg][kc], g4[gg]);
      }
      if (lane < 32){
        int n16 = wave*16 + (lane & 15);
        int mb = g*4;
        float bi = bias_s[n16], bf_ = bias_s[128+n16], bg = bias_s[256+n16], bo = bias_s[384+n16];
        float wi = wih_s[n16], wf = wih_s[128+n16], wg = wih_s[256+n16], wo = wih_s[384+n16];
        #pragma unroll
        for (int j = 0; j < 4; ++j){
          int m = mb + j;
          float yt = yt_s[m];
          float gi = g4[0][j] + bi + wi*yt;
          float gf = g4[1][j] + bf_ + wf*yt;
          float gg2 = g4[2][j] + bg + wg*yt;
          float go = g4[3][j] + bo + wo*yt;
          float cold = cds_s[m*128 + n16];
          float cn = fast_sig(gf)*cold + fast_sig(gi)*fast_tanh(gg2);
          float hn = fast_sig(go)*fast_tanh(cn);
          cds_s[m*128 + n16] = cn;
          sAB[m*264 + n16] = f2bf(hn);
          sAB[m*264 + 128 + n16] = f2bf(cn);
        }
      }
    }
    __syncthreads();  // 4

    // ---- F: o = [ct|d_new] @ l2W^T + l2b via MFMA ----
    {
      f4v of = {0.f,0.f,0.f,0.f};
      #pragma unroll
      for (int kc = 0; kc < 4; ++kc){
        s8v af = *(const s8v*)((const char*)sCT + (lane&15)*272 + kc*64 + g*16);
        of = MFMA16(af, bwF[kc], of);
      }
      #pragma unroll
      for (int kc = 4; kc < 8; ++kc){
        s8v af = *(const s8v*)((const char*)sAB + (lane&15)*528 + (kc-4)*64 + g*16);
        of = MFMA16(af, bwF[kc], of);
      }
      if (lane < 32){
        int n16 = wave*16 + (lane & 15);
        int mb = g*4;
        float l2bv = l2b[n16];
        #pragma unroll
        for (int j = 0; j < 4; ++j) o_s[(mb + j)*128 + n16] = of[j] + l2bv;
      }
    }
    __syncthreads();  // 5

    // ---- G: out = sigmoid(l3 . o + l3b) ----
    {
      int bb = wave;
      float o0 = o_s[bb*128 + 2*lane], o1 = o_s[bb*128 + 2*lane + 1];
      float p = l3W[2*lane]*o0 + l3W[2*lane + 1]*o1;
      #pragma unroll
      for (int off = 32; off; off >>= 1) p += __shfl_xor(p, off, 64);
      if (lane == 0) out_s[bb] = fast_sig(p + l3b[0]);
    }
    __syncthreads();  // 6
  }
  if (tid < 8) out[bbase + tid] = out_s[tid];
}

extern "C" void kernel_launch(void* const* d_in, const int* in_sizes, int n_in,
                              void* d_out, int out_size, void* d_ws, size_t ws_size,
                              hipStream_t stream){
  const float* X      = (const float*)d_in[0];
  const float* iaW1   = (const float*)d_in[1];
  const float* iab1   = (const float*)d_in[2];
  const float* iaW2   = (const float*)d_in[3];
  const float* encWih = (const float*)d_in[5];
  const float* encWhh = (const float*)d_in[6];
  const float* encbih = (const float*)d_in[7];
  const float* encbhh = (const float*)d_in[8];
  const float* taW1   = (const float*)d_in[9];
  const float* tab1   = (const float*)d_in[10];
  const float* taW2   = (const float*)d_in[11];
  const float* decWih = (const float*)d_in[13];
  const float* decWhh = (const float*)d_in[14];
  const float* decbih = (const float*)d_in[15];
  const float* decbhh = (const float*)d_in[16];
  const float* l1W    = (const float*)d_in[17];
  const float* l1b    = (const float*)d_in[18];
  const float* l2W    = (const float*)d_in[19];
  const float* l2b    = (const float*)d_in[20];
  const float* l3W    = (const float*)d_in[21];
  const float* l3b    = (const float*)d_in[22];

  char* ws = (char*)d_ws;
  ushort* Eenc = (ushort*)(ws);                // 32MB f16 [b][f][w]; later aliased by Edec
  ushort* Hsb  = (ushort*)(ws + 33554432);     // 32MB bf16 [b][w][h]
  ushort* HsT  = (ushort*)(ws + 2*33554432);   // 32MB bf16 [b][h][w]
  ushort* Edec = Eenc;                          // E_enc dead after k_enc

  k_upre<<<dim3(2048), dim3(256), 0, stream>>>(X, iaW1, Eenc);
  k_enc<<<dim3(256), dim3(512), 0, stream>>>(X, iaW1, iab1, iaW2,
                                             encWih, encWhh, encbih, encbhh,
                                             Eenc, Hsb);
  k_vpre<<<dim3(2048), dim3(512), 0, stream>>>(Hsb, taW1, Edec, HsT);
  k_dec<<<dim3(256), dim3(512), 0, stream>>>(taW1, tab1, taW2,
                                             decWih, decWhh, decbih, decbhh,
                                             l1W, l1b, l2W, l2b, l3W, l3b,
                                             Edec, HsT, (float*)d_out);
}

// Round 5
// 1161.402 us; speedup vs baseline: 3.8548x; 1.3848x over previous
//
#include <hip/hip_runtime.h>
#include <hip/hip_fp16.h>
#include <stdint.h>

typedef unsigned int uint;
typedef unsigned short ushort;

#define NB 2048
#define NW 64
#define NF 128
#define NH 128

typedef __attribute__((ext_vector_type(8))) short s8v;
typedef __attribute__((ext_vector_type(8))) _Float16 h8v;
typedef __attribute__((ext_vector_type(4))) float f4v;

#define MFMA16(a, b, c) __builtin_amdgcn_mfma_f32_16x16x32_bf16((a), (b), (c), 0, 0, 0)
#define MFMAH(a, b, c)  __builtin_amdgcn_mfma_f32_16x16x32_f16((a), (b), (c), 0, 0, 0)

union H8 { h8v v; __half2 h2[4]; uint4 u4; ushort us[8]; };

__device__ __forceinline__ float bfl(uint u){ return __uint_as_float(u << 16); }
__device__ __forceinline__ float bfh(uint u){ return __uint_as_float(u & 0xffff0000u); }
__device__ __forceinline__ ushort f2bf(float f){
  uint u = __float_as_uint(f);
  u += 0x7fffu + ((u >> 16) & 1u);
  return (ushort)(u >> 16);
}
__device__ __forceinline__ float bf2f(ushort s){ return __uint_as_float(((uint)s) << 16); }

__device__ __forceinline__ float fast_tanh(float x){
  float e = __expf(x + x);
  return 1.f - 2.f * __builtin_amdgcn_rcpf(e + 1.f);
}
__device__ __forceinline__ float fast_sig(float x){
  return __builtin_amdgcn_rcpf(1.f + __expf(-x));
}
__device__ __forceinline__ ushort expo_h(float x){  // f16 bits of exp(2x)
  return __half_as_ushort(__float2half(__expf(x + x)));
}

__device__ __forceinline__ s8v packW(const float* p){
  s8v r;
  #pragma unroll
  for (int i = 0; i < 8; ++i) r[i] = (short)f2bf(p[i]);
  return r;
}

// ------- E_enc[b][f][w] = exp(2 * sum_j ia_W1[w,j]*X[b,j,f]) (f16), MFMA -------
__global__ __launch_bounds__(256) void k_upre(const float* __restrict__ X,
                                              const float* __restrict__ iaW1,
                                              ushort* __restrict__ Eenc){
  __shared__ __align__(16) float sXT[128*68];   // [f][j] f32, stride 68 (16B-aligned, 2-way banks)
  const int tid = threadIdx.x, lane = tid & 63, wave = tid >> 6, g = lane >> 4;
  int b = blockIdx.x;
  const float* Xb = X + (size_t)b*NW*NF;
  for (int i = tid; i < NW*NF; i += 256){
    int j = i >> 7, f = i & 127;
    sXT[f*68 + j] = Xb[i];
  }
  s8v bw[2];
  {
    int w = wave*16 + (lane & 15);
    #pragma unroll
    for (int kb = 0; kb < 2; ++kb) bw[kb] = packW(iaW1 + w*320 + kb*32 + g*8);
  }
  __syncthreads();
  ushort* outb = Eenc + (size_t)b*NF*NW;
  int w = wave*16 + (lane & 15);
  #pragma unroll
  for (int mt = 0; mt < 8; ++mt){
    int f = mt*16 + (lane & 15);
    f4v acc = {0.f,0.f,0.f,0.f};
    #pragma unroll
    for (int kb = 0; kb < 2; ++kb){
      const float* p = &sXT[f*68 + kb*32 + g*8];
      s8v a;
      #pragma unroll
      for (int i = 0; i < 8; ++i) a[i] = (short)f2bf(p[i]);
      acc = MFMA16(a, bw[kb], acc);
    }
    int fr = mt*16 + g*4;
    #pragma unroll
    for (int j = 0; j < 4; ++j) outb[(fr + j)*64 + w] = expo_h(acc[j]);
  }
}

// ------- E_dec[b][w][h] = exp(2*vpre) (f16) via MFMA; HsT[b][h][w] transpose -------
__global__ __launch_bounds__(256) void k_vpre(const ushort* __restrict__ Hsb,
                                              const float* __restrict__ taW1,
                                              ushort* __restrict__ Edec,
                                              ushort* __restrict__ HsT){
  __shared__ __align__(16) ushort sH[64*136];   // [w][j] bf16, stride 136 (272B)
  const int tid = threadIdx.x, lane = tid & 63, wave = tid >> 6, g = lane >> 4;
  int b = blockIdx.x;
  const ushort* Hb = Hsb + (size_t)b*NW*NH;
  for (int i = tid; i < 1024; i += 256){       // 1024 x 16B chunks
    int w = i >> 4, c = i & 15;
    *(uint4*)&sH[w*136 + c*8] = *(const uint4*)(Hb + i*8);
  }
  s8v bw[2][4];
  #pragma unroll
  for (int nt = 0; nt < 2; ++nt){
    int h = wave*32 + nt*16 + (lane & 15);
    #pragma unroll
    for (int kb = 0; kb < 4; ++kb)
      bw[nt][kb] = packW(taW1 + h*384 + kb*32 + g*8);
  }
  __syncthreads();
  ushort* ho = HsT + (size_t)b*NH*NW;
  for (int k = 0; k < 32; ++k){
    int i2 = tid + 256*k;                      // i2 = h*64 + w
    int h = i2 >> 6, w2 = i2 & 63;
    ho[i2] = sH[w2*136 + h];
  }
  ushort* outb = Edec + (size_t)b*NW*NH;
  #pragma unroll
  for (int mt = 0; mt < 4; ++mt){
    s8v af[4];
    #pragma unroll
    for (int kb = 0; kb < 4; ++kb)
      af[kb] = *(const s8v*)&sH[(mt*16 + (lane&15))*136 + kb*32 + g*8];
    #pragma unroll
    for (int nt = 0; nt < 2; ++nt){
      f4v acc = {0.f,0.f,0.f,0.f};
      #pragma unroll
      for (int kb = 0; kb < 4; ++kb) acc = MFMA16(af[kb], bw[nt][kb], acc);
      int h = wave*32 + nt*16 + (lane&15);
      int wr = mt*16 + g*4;
      #pragma unroll
      for (int j = 0; j < 4; ++j) outb[(wr + j)*128 + h] = expo_h(acc[j]);
    }
  }
}

// =========================== encoder ===========================
__global__ __launch_bounds__(512, 2) void k_enc(
    const float* __restrict__ X, const float* __restrict__ iaW1,
    const float* __restrict__ iab1, const float* __restrict__ iaW2,
    const float* __restrict__ encWih, const float* __restrict__ encWhh,
    const float* __restrict__ encbih, const float* __restrict__ encbhh,
    const ushort* __restrict__ Eenc, ushort* __restrict__ Hsb){
  __shared__ __align__(16) ushort sUp[65536];    // E_enc slice [bb][f][w] f16, slot-XOR
  __shared__ __align__(16) ushort sAB[16*264];   // A-tile [c|h] / [xt|h] bf16
  __shared__ __align__(16) ushort uhc_h[8*64];   // exp(2*uhc) f16
  __shared__ __align__(16) float  c_s[8*128];
  __shared__ __align__(16) float  bias_s[512];
  __shared__ __align__(16) float  xrow[8*128];   // prefetched X row per batch

  const int tid = threadIdx.x, lane = tid & 63, wave = tid >> 6, g = lane >> 4;
  const int bbase = blockIdx.x * 8;

  for (int i = tid; i < 16*264; i += 512) sAB[i] = 0;
  for (int i = tid; i < 1024; i += 512) c_s[i] = 0.f;
  bias_s[tid] = encbih[tid] + encbhh[tid];
  {
    const ushort* up0 = Eenc + (size_t)bbase*NF*NW;
    #pragma unroll
    for (int k = 0; k < 16; ++k){
      int c = tid + k*512;
      int f = (c >> 3) & 127, s = c & 7;
      uint4 v = *(const uint4*)(up0 + (size_t)c*8);
      *(uint4*)((char*)sUp + (c>>3)*128 + ((s ^ (f & 7)) << 4)) = v;
    }
  }
  s8v bwC[4][8];
  #pragma unroll
  for (int gg = 0; gg < 4; ++gg){
    int j = gg*128 + wave*16 + (lane & 15);
    #pragma unroll
    for (int kc = 0; kc < 8; ++kc){
      const float* p = (kc < 4) ? (encWih + j*128 + kc*32) : (encWhh + j*128 + (kc-4)*32);
      bwC[gg][kc] = packW(p + g*8);
    }
  }
  s8v bwA[8];
  if (wave < 4){
    int n = wave*16 + (lane & 15);
    #pragma unroll
    for (int kc = 0; kc < 8; ++kc){
      int col = (kc < 4) ? (192 + kc*32) : (64 + (kc-4)*32);
      bwA[kc] = packW(iaW1 + n*320 + col + g*8);
    }
  }
  H8 w2f[2];
  #pragma unroll
  for (int kb = 0; kb < 2; ++kb)
    #pragma unroll
    for (int i = 0; i < 8; ++i)
      w2f[kb].v[i] = (_Float16)iaW2[kb*32 + g*8 + i];
  __syncthreads();

  for (int t = 0; t < NW; ++t){
    // ---- prefetch X row for this step (hidden under A+B) ----
    {
      const float* Xr = X + ((size_t)(bbase + wave)*NW + t)*NF;
      xrow[wave*128 + lane] = Xr[lane];
      xrow[wave*128 + 64 + lane] = Xr[64 + lane];
    }
    // ---- A: read [c|h]; waves 0-3: uhc via MFMA, store exp(2*uhc) f16 ----
    s8v aT[8];
    #pragma unroll
    for (int kc = 0; kc < 8; ++kc)
      aT[kc] = *(const s8v*)((const char*)sAB + (lane&15)*528 + kc*64 + g*16);
    if (wave < 4){
      f4v acc = {0.f,0.f,0.f,0.f};
      #pragma unroll
      for (int kc = 0; kc < 8; ++kc) acc = MFMA16(aT[kc], bwA[kc], acc);
      if (lane < 32){
        int n = wave*16 + (lane & 15);
        float b1v = iab1[n];
        int mb = g*4;
        #pragma unroll
        for (int j = 0; j < 4; ++j) uhc_h[(mb+j)*64 + n] = expo_h(acc[j] + b1v);
      }
    }
    __syncthreads();  // 1

    // ---- B: M[f] via f16 rcp + MFMAH; in-register softmax; write xt ----
    {
      int bb = wave;
      const char* Eb = (const char*)sUp + bb*16384;
      H8 sv[2];
      #pragma unroll
      for (int kb = 0; kb < 2; ++kb)
        sv[kb].u4 = *(const uint4*)((const char*)uhc_h + bb*128 + kb*64 + g*16);
      __half2 one2 = __float2half2_rn(1.f);
      f4v Mc[8];
      #pragma unroll
      for (int ft = 0; ft < 8; ++ft){
        int f = ft*16 + (lane & 15);
        const char* rowp = Eb + f*128;
        f4v acc = {0.f,0.f,0.f,0.f};
        #pragma unroll
        for (int kb = 0; kb < 2; ++kb){
          H8 e, a;
          e.v = *(const h8v*)(rowp + (((kb*4 + g) ^ (f & 7)) << 4));
          #pragma unroll
          for (int q = 0; q < 4; ++q) a.h2[q] = h2rcp(__hfma2(e.h2[q], sv[kb].h2[q], one2));
          acc = MFMAH(a.v, w2f[kb].v, acc);
        }
        Mc[ft] = acc;
      }
      float mn = Mc[0][0];
      #pragma unroll
      for (int ft = 0; ft < 8; ++ft)
        #pragma unroll
        for (int r = 0; r < 4; ++r) mn = fminf(mn, Mc[ft][r]);
      mn = fminf(mn, __shfl_xor(mn, 16, 64));
      mn = fminf(mn, __shfl_xor(mn, 32, 64));
      float xs[8][4]; float ssum = 0.f;
      #pragma unroll
      for (int ft = 0; ft < 8; ++ft)
        #pragma unroll
        for (int r = 0; r < 4; ++r){ float x = __expf(2.f*(mn - Mc[ft][r])); xs[ft][r] = x; ssum += x; }
      ssum += __shfl_xor(ssum, 16, 64);
      ssum += __shfl_xor(ssum, 32, 64);
      float inv = __builtin_amdgcn_rcpf(ssum);
      if ((lane & 15) == 0){
        #pragma unroll
        for (int ft = 0; ft < 8; ++ft){
          int f0 = ft*16 + g*4;
          float4 Xv = *(const float4*)&xrow[bb*128 + f0];
          uint lo = (uint)f2bf(xs[ft][0]*inv*Xv.x) | ((uint)f2bf(xs[ft][1]*inv*Xv.y) << 16);
          uint hi = (uint)f2bf(xs[ft][2]*inv*Xv.z) | ((uint)f2bf(xs[ft][3]*inv*Xv.w) << 16);
          *(uint2*)((char*)sAB + bb*528 + f0*2) = make_uint2(lo, hi);
        }
      }
    }
    __syncthreads();  // 2

    // ---- C: read xt frags ----
    s8v aX[4];
    #pragma unroll
    for (int kc = 0; kc < 4; ++kc)
      aX[kc] = *(const s8v*)((const char*)sAB + (lane&15)*528 + kc*64 + g*16);
    __syncthreads();  // 3

    // ---- gates via MFMA; in-wave LSTM update ----
    {
      f4v acc[4];
      #pragma unroll
      for (int gg = 0; gg < 4; ++gg) acc[gg] = (f4v){0.f,0.f,0.f,0.f};
      #pragma unroll
      for (int kc = 0; kc < 8; ++kc){
        s8v af = (kc < 4) ? aX[kc] : aT[kc];
        #pragma unroll
        for (int gg = 0; gg < 4; ++gg) acc[gg] = MFMA16(af, bwC[gg][kc], acc[gg]);
      }
      if (lane < 32){
        int n16 = wave*16 + (lane & 15);
        int mb = g*4;
        float bi = bias_s[n16], bf_ = bias_s[128+n16], bg = bias_s[256+n16], bo = bias_s[384+n16];
        #pragma unroll
        for (int j = 0; j < 4; ++j){
          int m = mb + j;
          float gi = acc[0][j] + bi;
          float gf = acc[1][j] + bf_;
          float gg2 = acc[2][j] + bg;
          float go = acc[3][j] + bo;
          float cold = c_s[m*128 + n16];
          float cn = fast_sig(gf)*cold + fast_sig(gi)*fast_tanh(gg2);
          float hn = fast_sig(go)*fast_tanh(cn);
          c_s[m*128 + n16] = cn;
          sAB[m*264 + n16] = f2bf(cn);
          sAB[m*264 + 128 + n16] = f2bf(hn);
          Hsb[((size_t)(bbase + m)*NW + t)*NH + n16] = f2bf(hn);
        }
      }
    }
    __syncthreads();  // 4
  }
}

// =========================== decoder ===========================
__global__ __launch_bounds__(512, 2) void k_dec(
    const float* __restrict__ taW1, const float* __restrict__ tab1,
    const float* __restrict__ taW2,
    const float* __restrict__ decWih, const float* __restrict__ decWhh,
    const float* __restrict__ decbih, const float* __restrict__ decbhh,
    const float* __restrict__ l1W, const float* __restrict__ l1b,
    const float* __restrict__ l2W, const float* __restrict__ l2b,
    const float* __restrict__ l3W, const float* __restrict__ l3b,
    const ushort* __restrict__ Edec, const ushort* __restrict__ HsT,
    float* __restrict__ out){
  __shared__ __align__(16) ushort sVp[65536];    // E_dec slice [bb][w][h] f16, slot-XOR
  __shared__ __align__(16) ushort sAB[16*264];   // [d|ds] bf16
  __shared__ __align__(16) ushort sCT[16*136];   // ct bf16
  __shared__ __align__(16) ushort vd_h[8*128];   // exp(2*vd) f16
  __shared__ __align__(16) ushort lb_bf[8*64];   // beta bf16
  __shared__ __align__(16) ushort sW2h[128];     // taW2 f16
  __shared__ __align__(16) float  o_s[8*128];
  __shared__ __align__(16) float  cds_s[1024];
  __shared__ __align__(16) float  bias_s[512];
  __shared__ __align__(16) float  wih_s[512];
  __shared__ float yt_s[8], out_s[8];

  const int tid = threadIdx.x, lane = tid & 63, wave = tid >> 6, g = lane >> 4;
  const int bbase = blockIdx.x * 8;

  for (int i = tid; i < 16*264; i += 512) sAB[i] = 0;
  for (int i = tid; i < 16*136; i += 512) sCT[i] = 0;
  for (int i = tid; i < 1024; i += 512) cds_s[i] = 0.f;
  bias_s[tid] = decbih[tid] + decbhh[tid];
  wih_s[tid] = decWih[tid];
  if (tid < 128) sW2h[tid] = __half_as_ushort(__float2half(taW2[tid]));
  if (tid < 8) out_s[tid] = 0.f;
  {
    const ushort* vp0 = Edec + (size_t)bbase*NW*NH;
    #pragma unroll
    for (int k = 0; k < 16; ++k){
      int c = tid + k*512;
      int w = (c >> 4) & 63, s = c & 15;
      uint4 v = *(const uint4*)(vp0 + (size_t)c*8);
      *(uint4*)((char*)sVp + (c >> 4)*256 + ((s ^ (w & 15)) << 4)) = v;
    }
  }
  s8v bwA[8];     // vd: B[k][h] = taW1[h][128+k]
  {
    int n = wave*16 + (lane & 15);
    #pragma unroll
    for (int kc = 0; kc < 8; ++kc)
      bwA[kc] = packW(taW1 + n*384 + 128 + kc*32 + g*8);
  }
  s8v bwD[4][4];  // gates: B[k][j] = decWhh[j][k]
  #pragma unroll
  for (int gg = 0; gg < 4; ++gg){
    int j = gg*128 + wave*16 + (lane & 15);
    #pragma unroll
    for (int kc = 0; kc < 4; ++kc)
      bwD[gg][kc] = packW(decWhh + j*128 + kc*32 + g*8);
  }
  s8v bwF[8];     // o: B[k][h] = l2W[h][k]
  {
    int n = wave*16 + (lane & 15);
    #pragma unroll
    for (int kc = 0; kc < 8; ++kc)
      bwF[kc] = packW(l2W + n*256 + kc*32 + g*8);
  }
  float l1w[8];
  #pragma unroll
  for (int ht = 0; ht < 8; ++ht) l1w[ht] = l1W[1 + ht*16 + (lane & 15)];
  __syncthreads();

  for (int t = 0; t < NW; ++t){
    // ---- A: vd via MFMA from [d|ds]; store exp(2*vd) f16 ----
    s8v aT[8];
    #pragma unroll
    for (int kc = 0; kc < 8; ++kc)
      aT[kc] = *(const s8v*)((const char*)sAB + (lane&15)*528 + kc*64 + g*16);
    {
      f4v acc = {0.f,0.f,0.f,0.f};
      #pragma unroll
      for (int kc = 0; kc < 8; ++kc) acc = MFMA16(aT[kc], bwA[kc], acc);
      if (lane < 32){
        int n = wave*16 + (lane & 15);
        float tb = tab1[n];
        int mb = g*4;
        #pragma unroll
        for (int j = 0; j < 4; ++j) vd_h[(mb+j)*128 + n] = expo_h(acc[j] + tb);
      }
    }
    __syncthreads();  // 1

    // ---- B+C (wave-local): softmax over w, then ct + yt ----
    {
      int bb = wave;
      // prefetch Hs B-frags early (t-invariant addresses; latency hides under softmax)
      const ushort* hb = HsT + (size_t)(bbase + bb)*NH*NW;
      s8v hbf[8][2];
      #pragma unroll
      for (int ht = 0; ht < 8; ++ht){
        int h = ht*16 + (lane & 15);
        #pragma unroll
        for (int kb = 0; kb < 2; ++kb)
          hbf[ht][kb] = *(const s8v*)(hb + h*64 + kb*32 + g*8);
      }
      const char* Eb = (const char*)sVp + bb*16384;
      H8 sv[4];
      #pragma unroll
      for (int kb = 0; kb < 4; ++kb)
        sv[kb].u4 = *(const uint4*)((const char*)vd_h + bb*256 + kb*64 + g*16);
      __half2 one2 = __float2half2_rn(1.f);
      f4v Mc[4];
      #pragma unroll
      for (int wt = 0; wt < 4; ++wt){
        int w = wt*16 + (lane & 15);
        const char* rowp = Eb + w*256;
        f4v acc = {0.f,0.f,0.f,0.f};
        #pragma unroll
        for (int kb = 0; kb < 4; ++kb){
          H8 e, a, wv;
          wv.u4 = *(const uint4*)&sW2h[kb*32 + g*8];
          e.v = *(const h8v*)(rowp + (((kb*4 + g) ^ (w & 15)) << 4));
          #pragma unroll
          for (int q = 0; q < 4; ++q) a.h2[q] = h2rcp(__hfma2(e.h2[q], sv[kb].h2[q], one2));
          acc = MFMAH(a.v, wv.v, acc);
        }
        Mc[wt] = acc;
      }
      float mn = Mc[0][0];
      #pragma unroll
      for (int wt = 0; wt < 4; ++wt)
        #pragma unroll
        for (int r = 0; r < 4; ++r) mn = fminf(mn, Mc[wt][r]);
      mn = fminf(mn, __shfl_xor(mn, 16, 64));
      mn = fminf(mn, __shfl_xor(mn, 32, 64));
      float xs[4][4]; float ssum = 0.f;
      #pragma unroll
      for (int wt = 0; wt < 4; ++wt)
        #pragma unroll
        for (int r = 0; r < 4; ++r){ float x = __expf(2.f*(mn - Mc[wt][r])); xs[wt][r] = x; ssum += x; }
      ssum += __shfl_xor(ssum, 16, 64);
      ssum += __shfl_xor(ssum, 32, 64);
      float inv = __builtin_amdgcn_rcpf(ssum);
      if ((lane & 15) == 0){
        #pragma unroll
        for (int wt = 0; wt < 4; ++wt){
          int w0 = wt*16 + g*4;
          uint lo = (uint)f2bf(xs[wt][0]*inv) | ((uint)f2bf(xs[wt][1]*inv) << 16);
          uint hi = (uint)f2bf(xs[wt][2]*inv) | ((uint)f2bf(xs[wt][3]*inv) << 16);
          *(uint2*)((char*)lb_bf + bb*128 + w0*2) = make_uint2(lo, hi);
        }
      }
      // same-wave: beta back as A-frags (compiler inserts lgkmcnt wait)
      s8v ba[2];
      #pragma unroll
      for (int kb = 0; kb < 2; ++kb)
        ba[kb] = *(const s8v*)((const char*)lb_bf + bb*128 + kb*64 + g*16);
      float p = 0.f;
      #pragma unroll
      for (int ht = 0; ht < 8; ++ht){
        f4v acc = {0.f,0.f,0.f,0.f};
        #pragma unroll
        for (int kb = 0; kb < 2; ++kb) acc = MFMA16(ba[kb], hbf[ht][kb], acc);
        float ctv = acc[0];
        if (lane < 16) sCT[bb*136 + ht*16 + (lane&15)] = f2bf(ctv);
        p += l1w[ht] * ctv;
      }
      p += __shfl_xor(p, 1, 64);
      p += __shfl_xor(p, 2, 64);
      p += __shfl_xor(p, 4, 64);
      p += __shfl_xor(p, 8, 64);
      if (lane == 0) yt_s[bb] = p + l1W[0]*out_s[bb] + l1b[0];
    }
    __syncthreads();  // 2

    // ---- D: gates via MFMA + in-wave update ----
    {
      f4v g4[4];
      #pragma unroll
      for (int gg = 0; gg < 4; ++gg) g4[gg] = (f4v){0.f,0.f,0.f,0.f};
      #pragma unroll
      for (int kc = 0; kc < 4; ++kc){
        #pragma unroll
        for (int gg = 0; gg < 4; ++gg) g4[gg] = MFMA16(aT[kc], bwD[gg][kc], g4[gg]);
      }
      if (lane < 32){
        int n16 = wave*16 + (lane & 15);
        int mb = g*4;
        float bi = bias_s[n16], bf_ = bias_s[128+n16], bg = bias_s[256+n16], bo = bias_s[384+n16];
        float wi = wih_s[n16], wf = wih_s[128+n16], wg = wih_s[256+n16], wo = wih_s[384+n16];
        #pragma unroll
        for (int j = 0; j < 4; ++j){
          int m = mb + j;
          float yt = yt_s[m];
          float gi = g4[0][j] + bi + wi*yt;
          float gf = g4[1][j] + bf_ + wf*yt;
          float gg2 = g4[2][j] + bg + wg*yt;
          float go = g4[3][j] + bo + wo*yt;
          float cold = cds_s[m*128 + n16];
          float cn = fast_sig(gf)*cold + fast_sig(gi)*fast_tanh(gg2);
          float hn = fast_sig(go)*fast_tanh(cn);
          cds_s[m*128 + n16] = cn;
          sAB[m*264 + n16] = f2bf(hn);
          sAB[m*264 + 128 + n16] = f2bf(cn);
        }
      }
    }
    __syncthreads();  // 3

    // ---- F: o = [ct|d_new] @ l2W^T + l2b via MFMA ----
    {
      f4v of = {0.f,0.f,0.f,0.f};
      #pragma unroll
      for (int kc = 0; kc < 4; ++kc){
        s8v af = *(const s8v*)((const char*)sCT + (lane&15)*272 + kc*64 + g*16);
        of = MFMA16(af, bwF[kc], of);
      }
      #pragma unroll
      for (int kc = 4; kc < 8; ++kc){
        s8v af = *(const s8v*)((const char*)sAB + (lane&15)*528 + (kc-4)*64 + g*16);
        of = MFMA16(af, bwF[kc], of);
      }
      if (lane < 32){
        int n16 = wave*16 + (lane & 15);
        int mb = g*4;
        float l2bv = l2b[n16];
        #pragma unroll
        for (int j = 0; j < 4; ++j) o_s[(mb + j)*128 + n16] = of[j] + l2bv;
      }
    }
    __syncthreads();  // 4

    // ---- G: out = sigmoid(l3 . o + l3b)  (no trailing barrier; b1 of t+1 fences) ----
    {
      int bb = wave;
      float o0 = o_s[bb*128 + 2*lane], o1 = o_s[bb*128 + 2*lane + 1];
      float p = l3W[2*lane]*o0 + l3W[2*lane + 1]*o1;
      #pragma unroll
      for (int off = 32; off; off >>= 1) p += __shfl_xor(p, off, 64);
      if (lane == 0) out_s[bb] = fast_sig(p + l3b[0]);
    }
  }
  __syncthreads();
  if (tid < 8) out[bbase + tid] = out_s[tid];
}

extern "C" void kernel_launch(void* const* d_in, const int* in_sizes, int n_in,
                              void* d_out, int out_size, void* d_ws, size_t ws_size,
                              hipStream_t stream){
  const float* X      = (const float*)d_in[0];
  const float* iaW1   = (const float*)d_in[1];
  const float* iab1   = (const float*)d_in[2];
  const float* iaW2   = (const float*)d_in[3];
  const float* encWih = (const float*)d_in[5];
  const float* encWhh = (const float*)d_in[6];
  const float* encbih = (const float*)d_in[7];
  const float* encbhh = (const float*)d_in[8];
  const float* taW1   = (const float*)d_in[9];
  const float* tab1   = (const float*)d_in[10];
  const float* taW2   = (const float*)d_in[11];
  const float* decWih = (const float*)d_in[13];
  const float* decWhh = (const float*)d_in[14];
  const float* decbih = (const float*)d_in[15];
  const float* decbhh = (const float*)d_in[16];
  const float* l1W    = (const float*)d_in[17];
  const float* l1b    = (const float*)d_in[18];
  const float* l2W    = (const float*)d_in[19];
  const float* l2b    = (const float*)d_in[20];
  const float* l3W    = (const float*)d_in[21];
  const float* l3b    = (const float*)d_in[22];

  char* ws = (char*)d_ws;
  ushort* Eenc = (ushort*)(ws);                // 32MB f16 [b][f][w]; aliased by Edec later
  ushort* Hsb  = (ushort*)(ws + 33554432);     // 32MB bf16 [b][w][h]
  ushort* HsT  = (ushort*)(ws + 2*33554432);   // 32MB bf16 [b][h][w]
  ushort* Edec = Eenc;

  k_upre<<<dim3(2048), dim3(256), 0, stream>>>(X, iaW1, Eenc);
  k_enc<<<dim3(256), dim3(512), 0, stream>>>(X, iaW1, iab1, iaW2,
                                             encWih, encWhh, encbih, encbhh,
                                             Eenc, Hsb);
  k_vpre<<<dim3(2048), dim3(256), 0, stream>>>(Hsb, taW1, Edec, HsT);
  k_dec<<<dim3(256), dim3(512), 0, stream>>>(taW1, tab1, taW2,
                                             decWih, decWhh, decbih, decbhh,
                                             l1W, l1b, l2W, l2b, l3W, l3b,
                                             Edec, HsT, (float*)d_out);
}

// Round 6
// 1152.718 us; speedup vs baseline: 3.8838x; 1.0075x over previous
//
#include <hip/hip_runtime.h>
#include <hip/hip_fp16.h>
#include <stdint.h>

typedef unsigned int uint;
typedef unsigned short ushort;

#define NB 2048
#define NW 64
#define NF 128
#define NH 128

typedef __attribute__((ext_vector_type(8))) short s8v;
typedef __attribute__((ext_vector_type(8))) _Float16 h8v;
typedef __attribute__((ext_vector_type(4))) float f4v;

#define MFMA16(a, b, c) __builtin_amdgcn_mfma_f32_16x16x32_bf16((a), (b), (c), 0, 0, 0)
#define MFMAH(a, b, c)  __builtin_amdgcn_mfma_f32_16x16x32_f16((a), (b), (c), 0, 0, 0)

union H8 { h8v v; __half2 h2[4]; uint4 u4; ushort us[8]; };

__device__ __forceinline__ float bfl(uint u){ return __uint_as_float(u << 16); }
__device__ __forceinline__ float bfh(uint u){ return __uint_as_float(u & 0xffff0000u); }
__device__ __forceinline__ ushort f2bf(float f){
  uint u = __float_as_uint(f);
  u += 0x7fffu + ((u >> 16) & 1u);
  return (ushort)(u >> 16);
}
__device__ __forceinline__ float bf2f(ushort s){ return __uint_as_float(((uint)s) << 16); }

__device__ __forceinline__ float fast_tanh(float x){
  float e = __expf(x + x);
  return 1.f - 2.f * __builtin_amdgcn_rcpf(e + 1.f);
}
__device__ __forceinline__ float fast_sig(float x){
  return __builtin_amdgcn_rcpf(1.f + __expf(-x));
}
__device__ __forceinline__ ushort expo_h(float x){  // f16 bits of exp(2x)
  return __half_as_ushort(__float2half(__expf(x + x)));
}

__device__ __forceinline__ s8v packW(const float* p){
  s8v r;
  #pragma unroll
  for (int i = 0; i < 8; ++i) r[i] = (short)f2bf(p[i]);
  return r;
}

// ------- E_enc[b][f][w] = exp(2 * sum_j ia_W1[w,j]*X[b,j,f]) (f16), MFMA -------
__global__ __launch_bounds__(256) void k_upre(const float* __restrict__ X,
                                              const float* __restrict__ iaW1,
                                              ushort* __restrict__ Eenc){
  __shared__ __align__(16) float sXT[128*68];
  const int tid = threadIdx.x, lane = tid & 63, wave = tid >> 6, g = lane >> 4;
  int b = blockIdx.x;
  const float* Xb = X + (size_t)b*NW*NF;
  for (int i = tid; i < NW*NF; i += 256){
    int j = i >> 7, f = i & 127;
    sXT[f*68 + j] = Xb[i];
  }
  s8v bw[2];
  {
    int w = wave*16 + (lane & 15);
    #pragma unroll
    for (int kb = 0; kb < 2; ++kb) bw[kb] = packW(iaW1 + w*320 + kb*32 + g*8);
  }
  __syncthreads();
  ushort* outb = Eenc + (size_t)b*NF*NW;
  int w = wave*16 + (lane & 15);
  #pragma unroll
  for (int mt = 0; mt < 8; ++mt){
    int f = mt*16 + (lane & 15);
    f4v acc = {0.f,0.f,0.f,0.f};
    #pragma unroll
    for (int kb = 0; kb < 2; ++kb){
      const float* p = &sXT[f*68 + kb*32 + g*8];
      s8v a;
      #pragma unroll
      for (int i = 0; i < 8; ++i) a[i] = (short)f2bf(p[i]);
      acc = MFMA16(a, bw[kb], acc);
    }
    int fr = mt*16 + g*4;
    #pragma unroll
    for (int j = 0; j < 4; ++j) outb[(fr + j)*64 + w] = expo_h(acc[j]);
  }
}

// ------- E_dec[b][w][h] = exp(2*vpre) (f16) via MFMA; HsT[b][h][w] transpose -------
__global__ __launch_bounds__(256) void k_vpre(const ushort* __restrict__ Hsb,
                                              const float* __restrict__ taW1,
                                              ushort* __restrict__ Edec,
                                              ushort* __restrict__ HsT){
  __shared__ __align__(16) ushort sH[64*136];
  const int tid = threadIdx.x, lane = tid & 63, wave = tid >> 6, g = lane >> 4;
  int b = blockIdx.x;
  const ushort* Hb = Hsb + (size_t)b*NW*NH;
  for (int i = tid; i < 1024; i += 256){
    int w = i >> 4, c = i & 15;
    *(uint4*)&sH[w*136 + c*8] = *(const uint4*)(Hb + i*8);
  }
  s8v bw[2][4];
  #pragma unroll
  for (int nt = 0; nt < 2; ++nt){
    int h = wave*32 + nt*16 + (lane & 15);
    #pragma unroll
    for (int kb = 0; kb < 4; ++kb)
      bw[nt][kb] = packW(taW1 + h*384 + kb*32 + g*8);
  }
  __syncthreads();
  ushort* ho = HsT + (size_t)b*NH*NW;
  for (int k = 0; k < 32; ++k){
    int i2 = tid + 256*k;
    int h = i2 >> 6, w2 = i2 & 63;
    ho[i2] = sH[w2*136 + h];
  }
  ushort* outb = Edec + (size_t)b*NW*NH;
  #pragma unroll
  for (int mt = 0; mt < 4; ++mt){
    s8v af[4];
    #pragma unroll
    for (int kb = 0; kb < 4; ++kb)
      af[kb] = *(const s8v*)&sH[(mt*16 + (lane&15))*136 + kb*32 + g*8];
    #pragma unroll
    for (int nt = 0; nt < 2; ++nt){
      f4v acc = {0.f,0.f,0.f,0.f};
      #pragma unroll
      for (int kb = 0; kb < 4; ++kb) acc = MFMA16(af[kb], bw[nt][kb], acc);
      int h = wave*32 + nt*16 + (lane&15);
      int wr = mt*16 + g*4;
      #pragma unroll
      for (int j = 0; j < 4; ++j) outb[(wr + j)*128 + h] = expo_h(acc[j]);
    }
  }
}

// =========================== encoder ===========================
__global__ __launch_bounds__(512, 2) void k_enc(
    const float* __restrict__ X, const float* __restrict__ iaW1,
    const float* __restrict__ iab1, const float* __restrict__ iaW2,
    const float* __restrict__ encWih, const float* __restrict__ encWhh,
    const float* __restrict__ encbih, const float* __restrict__ encbhh,
    const ushort* __restrict__ Eenc, ushort* __restrict__ Hsb){
  __shared__ __align__(16) ushort sUp[65536];    // E_enc slice [bb][f][w] f16, slot-XOR
  __shared__ __align__(16) ushort sAB[16*264];   // A-tile [c|h] / [xt|h] bf16
  __shared__ __align__(16) ushort uhc_h[8*64];   // exp(2*uhc) f16
  __shared__ __align__(16) float  xrow[8*128];   // prefetched X row per batch

  const int tid = threadIdx.x, lane = tid & 63, wave = tid >> 6, g = lane >> 4;
  const int bbase = blockIdx.x * 8;
  const int n16 = wave*16 + (lane & 15);

  for (int i = tid; i < 16*264; i += 512) sAB[i] = 0;
  {
    const ushort* up0 = Eenc + (size_t)bbase*NF*NW;
    #pragma unroll
    for (int k = 0; k < 16; ++k){
      int c = tid + k*512;
      int f = (c >> 3) & 127, s = c & 7;
      uint4 v = *(const uint4*)(up0 + (size_t)c*8);
      *(uint4*)((char*)sUp + (c>>3)*128 + ((s ^ (f & 7)) << 4)) = v;
    }
  }
  // per-lane constants (registers)
  float bias_r[4];
  #pragma unroll
  for (int gg = 0; gg < 4; ++gg)
    bias_r[gg] = encbih[gg*128 + n16] + encbhh[gg*128 + n16];
  float b1_r = iab1[n16 & 63];
  float c_r[4] = {0.f, 0.f, 0.f, 0.f};
  // weight fragments
  s8v bwC[4][8];
  #pragma unroll
  for (int gg = 0; gg < 4; ++gg){
    int j = gg*128 + n16;
    #pragma unroll
    for (int kc = 0; kc < 8; ++kc){
      const float* p = (kc < 4) ? (encWih + j*128 + kc*32) : (encWhh + j*128 + (kc-4)*32);
      bwC[gg][kc] = packW(p + g*8);
    }
  }
  s8v bwA[8];
  if (wave < 4){
    #pragma unroll
    for (int kc = 0; kc < 8; ++kc){
      int col = (kc < 4) ? (192 + kc*32) : (64 + (kc-4)*32);
      bwA[kc] = packW(iaW1 + n16*320 + col + g*8);
    }
  }
  H8 w2f[2];
  #pragma unroll
  for (int kb = 0; kb < 2; ++kb)
    #pragma unroll
    for (int i = 0; i < 8; ++i)
      w2f[kb].v[i] = (_Float16)iaW2[kb*32 + g*8 + i];
  __syncthreads();

  for (int t = 0; t < NW; ++t){
    // ---- prefetch X row (hidden under A+B) ----
    {
      const float* Xr = X + ((size_t)(bbase + wave)*NW + t)*NF;
      xrow[wave*128 + lane] = Xr[lane];
      xrow[wave*128 + 64 + lane] = Xr[64 + lane];
    }
    // ---- A: read [c|h]; waves 0-3: uhc via MFMA, store exp(2*uhc) f16 ----
    s8v aT[8];
    #pragma unroll
    for (int kc = 0; kc < 8; ++kc)
      aT[kc] = *(const s8v*)((const char*)sAB + (lane&15)*528 + kc*64 + g*16);
    if (wave < 4){
      f4v acc = {0.f,0.f,0.f,0.f};
      #pragma unroll
      for (int kc = 0; kc < 8; ++kc) acc = MFMA16(aT[kc], bwA[kc], acc);
      if (lane < 32){
        int mb = g*4;
        #pragma unroll
        for (int j = 0; j < 4; ++j) uhc_h[(mb+j)*64 + n16] = expo_h(acc[j] + b1_r);
      }
    }
    __syncthreads();  // 1

    // ---- B: M[f] via f16 rcp + MFMAH; no-max softmax; write xt ----
    {
      int bb = wave;
      const char* Eb = (const char*)sUp + bb*16384;
      H8 sv[2];
      #pragma unroll
      for (int kb = 0; kb < 2; ++kb)
        sv[kb].u4 = *(const uint4*)((const char*)uhc_h + bb*128 + kb*64 + g*16);
      __half2 one2 = __float2half2_rn(1.f);
      f4v Mc[8];
      #pragma unroll
      for (int ft = 0; ft < 8; ++ft){
        int f = ft*16 + (lane & 15);
        const char* rowp = Eb + f*128;
        f4v acc = {0.f,0.f,0.f,0.f};
        #pragma unroll
        for (int kb = 0; kb < 2; ++kb){
          H8 e, a;
          e.v = *(const h8v*)(rowp + (((kb*4 + g) ^ (f & 7)) << 4));
          #pragma unroll
          for (int q = 0; q < 4; ++q) a.h2[q] = h2rcp(__hfma2(e.h2[q], sv[kb].h2[q], one2));
          acc = MFMAH(a.v, w2f[kb].v, acc);
        }
        Mc[ft] = acc;
      }
      // no max-shift: |2M| <= ~6, exp safe in f32
      float xs[8][4]; float ssum = 0.f;
      #pragma unroll
      for (int ft = 0; ft < 8; ++ft)
        #pragma unroll
        for (int r = 0; r < 4; ++r){ float x = __expf(-2.f*Mc[ft][r]); xs[ft][r] = x; ssum += x; }
      ssum += __shfl_xor(ssum, 16, 64);
      ssum += __shfl_xor(ssum, 32, 64);
      float inv = __builtin_amdgcn_rcpf(ssum);
      if ((lane & 15) == 0){
        #pragma unroll
        for (int ft = 0; ft < 8; ++ft){
          int f0 = ft*16 + g*4;
          float4 Xv = *(const float4*)&xrow[bb*128 + f0];
          uint lo = (uint)f2bf(xs[ft][0]*inv*Xv.x) | ((uint)f2bf(xs[ft][1]*inv*Xv.y) << 16);
          uint hi = (uint)f2bf(xs[ft][2]*inv*Xv.z) | ((uint)f2bf(xs[ft][3]*inv*Xv.w) << 16);
          *(uint2*)((char*)sAB + bb*528 + f0*2) = make_uint2(lo, hi);
        }
      }
    }
    __syncthreads();  // 2

    // ---- C: read xt frags ----
    s8v aX[4];
    #pragma unroll
    for (int kc = 0; kc < 4; ++kc)
      aX[kc] = *(const s8v*)((const char*)sAB + (lane&15)*528 + kc*64 + g*16);
    __syncthreads();  // 3

    // ---- gates via MFMA; in-wave LSTM update (c in registers) ----
    {
      f4v acc[4];
      #pragma unroll
      for (int gg = 0; gg < 4; ++gg) acc[gg] = (f4v){0.f,0.f,0.f,0.f};
      #pragma unroll
      for (int kc = 0; kc < 8; ++kc){
        s8v af = (kc < 4) ? aX[kc] : aT[kc];
        #pragma unroll
        for (int gg = 0; gg < 4; ++gg) acc[gg] = MFMA16(af, bwC[gg][kc], acc[gg]);
      }
      if (lane < 32){
        int mb = g*4;
        #pragma unroll
        for (int j = 0; j < 4; ++j){
          int m = mb + j;
          float gi = acc[0][j] + bias_r[0];
          float gf = acc[1][j] + bias_r[1];
          float gg2 = acc[2][j] + bias_r[2];
          float go = acc[3][j] + bias_r[3];
          float cold = c_r[j];
          float cn = fast_sig(gf)*cold + fast_sig(gi)*fast_tanh(gg2);
          float hn = fast_sig(go)*fast_tanh(cn);
          c_r[j] = cn;
          sAB[m*264 + n16] = f2bf(cn);
          sAB[m*264 + 128 + n16] = f2bf(hn);
          Hsb[((size_t)(bbase + m)*NW + t)*NH + n16] = f2bf(hn);
        }
      }
    }
    __syncthreads();  // 4
  }
}

// =========================== decoder ===========================
__global__ __launch_bounds__(512, 2) void k_dec(
    const float* __restrict__ taW1, const float* __restrict__ tab1,
    const float* __restrict__ taW2,
    const float* __restrict__ decWih, const float* __restrict__ decWhh,
    const float* __restrict__ decbih, const float* __restrict__ decbhh,
    const float* __restrict__ l1W, const float* __restrict__ l1b,
    const float* __restrict__ l2W, const float* __restrict__ l2b,
    const float* __restrict__ l3W, const float* __restrict__ l3b,
    const ushort* __restrict__ Edec, const ushort* __restrict__ HsT,
    float* __restrict__ out){
  __shared__ __align__(16) ushort sVp[65536];    // E_dec slice [bb][w][h] f16, slot-XOR
  __shared__ __align__(16) ushort sAB[16*264];   // [d|ds] bf16
  __shared__ __align__(16) ushort sCT[16*136];   // ct bf16
  __shared__ __align__(16) ushort vd_h[8*128];   // exp(2*vd) f16
  __shared__ __align__(16) ushort lb_bf[8*64];   // beta bf16
  __shared__ __align__(16) float  op_s[8][8];    // per-wave l3.o partials
  __shared__ __align__(16) float  yt_s[8];

  const int tid = threadIdx.x, lane = tid & 63, wave = tid >> 6, g = lane >> 4;
  const int bbase = blockIdx.x * 8;
  const int n16 = wave*16 + (lane & 15);

  for (int i = tid; i < 16*264; i += 512) sAB[i] = 0;
  for (int i = tid; i < 16*136; i += 512) sCT[i] = 0;
  {
    const ushort* vp0 = Edec + (size_t)bbase*NW*NH;
    #pragma unroll
    for (int k = 0; k < 16; ++k){
      int c = tid + k*512;
      int w = (c >> 4) & 63, s = c & 15;
      uint4 v = *(const uint4*)(vp0 + (size_t)c*8);
      *(uint4*)((char*)sVp + (c >> 4)*256 + ((s ^ (w & 15)) << 4)) = v;
    }
  }
  // per-lane constants (registers)
  float bias_r[4], wih_r[4];
  #pragma unroll
  for (int gg = 0; gg < 4; ++gg){
    bias_r[gg] = decbih[gg*128 + n16] + decbhh[gg*128 + n16];
    wih_r[gg]  = decWih[gg*128 + n16];
  }
  float tab1_r = tab1[n16];
  float l2b_r  = l2b[n16];
  float l3w_r  = l3W[n16];
  float l1w0 = l1W[0], l1b0 = l1b[0], l3b0 = l3b[0];
  float cds_r[4] = {0.f, 0.f, 0.f, 0.f};
  // weight fragments
  s8v bwA[8];
  #pragma unroll
  for (int kc = 0; kc < 8; ++kc)
    bwA[kc] = packW(taW1 + n16*384 + 128 + kc*32 + g*8);
  s8v bwD[4][4];
  #pragma unroll
  for (int gg = 0; gg < 4; ++gg){
    int j = gg*128 + n16;
    #pragma unroll
    for (int kc = 0; kc < 4; ++kc)
      bwD[gg][kc] = packW(decWhh + j*128 + kc*32 + g*8);
  }
  s8v bwF[8];
  #pragma unroll
  for (int kc = 0; kc < 8; ++kc)
    bwF[kc] = packW(l2W + n16*256 + kc*32 + g*8);
  H8 w2df[4];
  #pragma unroll
  for (int kb = 0; kb < 4; ++kb)
    #pragma unroll
    for (int i = 0; i < 8; ++i)
      w2df[kb].v[i] = (_Float16)taW2[kb*32 + g*8 + i];
  float l1w[8];
  #pragma unroll
  for (int ht = 0; ht < 8; ++ht) l1w[ht] = l1W[1 + ht*16 + (lane & 15)];
  __syncthreads();

  for (int t = 0; t < NW; ++t){
    // ---- A: vd via MFMA from [d|ds]; store exp(2*vd) f16 ----
    s8v aT[8];
    #pragma unroll
    for (int kc = 0; kc < 8; ++kc)
      aT[kc] = *(const s8v*)((const char*)sAB + (lane&15)*528 + kc*64 + g*16);
    {
      f4v acc = {0.f,0.f,0.f,0.f};
      #pragma unroll
      for (int kc = 0; kc < 8; ++kc) acc = MFMA16(aT[kc], bwA[kc], acc);
      if (lane < 32){
        int mb = g*4;
        #pragma unroll
        for (int j = 0; j < 4; ++j) vd_h[(mb+j)*128 + n16] = expo_h(acc[j] + tab1_r);
      }
    }
    __syncthreads();  // 1

    // ---- B+C (wave-local): no-max softmax over w, then ct + yt ----
    {
      int bb = wave;
      // prefetch Hs B-frags early (latency hides under softmax)
      const ushort* hb = HsT + (size_t)(bbase + bb)*NH*NW;
      s8v hbf[8][2];
      #pragma unroll
      for (int ht = 0; ht < 8; ++ht){
        int h = ht*16 + (lane & 15);
        #pragma unroll
        for (int kb = 0; kb < 2; ++kb)
          hbf[ht][kb] = *(const s8v*)(hb + h*64 + kb*32 + g*8);
      }
      const char* Eb = (const char*)sVp + bb*16384;
      H8 sv[4];
      #pragma unroll
      for (int kb = 0; kb < 4; ++kb)
        sv[kb].u4 = *(const uint4*)((const char*)vd_h + bb*256 + kb*64 + g*16);
      __half2 one2 = __float2half2_rn(1.f);
      f4v Mc[4];
      #pragma unroll
      for (int wt = 0; wt < 4; ++wt){
        int w = wt*16 + (lane & 15);
        const char* rowp = Eb + w*256;
        f4v acc = {0.f,0.f,0.f,0.f};
        #pragma unroll
        for (int kb = 0; kb < 4; ++kb){
          H8 e, a;
          e.v = *(const h8v*)(rowp + (((kb*4 + g) ^ (w & 15)) << 4));
          #pragma unroll
          for (int q = 0; q < 4; ++q) a.h2[q] = h2rcp(__hfma2(e.h2[q], sv[kb].h2[q], one2));
          acc = MFMAH(a.v, w2df[kb].v, acc);
        }
        Mc[wt] = acc;
      }
      float xs[4][4]; float ssum = 0.f;
      #pragma unroll
      for (int wt = 0; wt < 4; ++wt)
        #pragma unroll
        for (int r = 0; r < 4; ++r){ float x = __expf(-2.f*Mc[wt][r]); xs[wt][r] = x; ssum += x; }
      ssum += __shfl_xor(ssum, 16, 64);
      ssum += __shfl_xor(ssum, 32, 64);
      float inv = __builtin_amdgcn_rcpf(ssum);
      if ((lane & 15) == 0){
        #pragma unroll
        for (int wt = 0; wt < 4; ++wt){
          int w0 = wt*16 + g*4;
          uint lo = (uint)f2bf(xs[wt][0]*inv) | ((uint)f2bf(xs[wt][1]*inv) << 16);
          uint hi = (uint)f2bf(xs[wt][2]*inv) | ((uint)f2bf(xs[wt][3]*inv) << 16);
          *(uint2*)((char*)lb_bf + bb*128 + w0*2) = make_uint2(lo, hi);
        }
      }
      // same-wave: beta back as A-frags
      s8v ba[2];
      #pragma unroll
      for (int kb = 0; kb < 2; ++kb)
        ba[kb] = *(const s8v*)((const char*)lb_bf + bb*128 + kb*64 + g*16);
      float p = 0.f;
      #pragma unroll
      for (int ht = 0; ht < 8; ++ht){
        f4v acc = {0.f,0.f,0.f,0.f};
        #pragma unroll
        for (int kb = 0; kb < 2; ++kb) acc = MFMA16(ba[kb], hbf[ht][kb], acc);
        float ctv = acc[0];
        if (lane < 16) sCT[bb*136 + ht*16 + (lane&15)] = f2bf(ctv);
        p += l1w[ht] * ctv;
      }
      p += __shfl_xor(p, 1, 64);
      p += __shfl_xor(p, 2, 64);
      p += __shfl_xor(p, 4, 64);
      p += __shfl_xor(p, 8, 64);
      if (lane == 0) yt_s[bb] = p + l1b0;
    }
    __syncthreads();  // 2

    // ---- D: gates via MFMA + in-wave update (cds in regs; out_prev from op_s) ----
    {
      f4v g4[4];
      #pragma unroll
      for (int gg = 0; gg < 4; ++gg) g4[gg] = (f4v){0.f,0.f,0.f,0.f};
      #pragma unroll
      for (int kc = 0; kc < 4; ++kc){
        #pragma unroll
        for (int gg = 0; gg < 4; ++gg) g4[gg] = MFMA16(aT[kc], bwD[gg][kc], g4[gg]);
      }
      if (lane < 32){
        int mb = g*4;
        float4 so = make_float4(0.f, 0.f, 0.f, 0.f);
        #pragma unroll
        for (int w = 0; w < 8; ++w){
          float4 v = *(const float4*)((const char*)op_s + w*32 + g*16);
          so.x += v.x; so.y += v.y; so.z += v.z; so.w += v.w;
        }
        float soa[4] = {so.x, so.y, so.z, so.w};
        #pragma unroll
        for (int j = 0; j < 4; ++j){
          int m = mb + j;
          float outp = (t == 0) ? 0.f : fast_sig(soa[j] + l3b0);
          float yt = yt_s[m] + l1w0*outp;
          float gi = g4[0][j] + bias_r[0] + wih_r[0]*yt;
          float gf = g4[1][j] + bias_r[1] + wih_r[1]*yt;
          float gg2 = g4[2][j] + bias_r[2] + wih_r[2]*yt;
          float go = g4[3][j] + bias_r[3] + wih_r[3]*yt;
          float cold = cds_r[j];
          float cn = fast_sig(gf)*cold + fast_sig(gi)*fast_tanh(gg2);
          float hn = fast_sig(go)*fast_tanh(cn);
          cds_r[j] = cn;
          sAB[m*264 + n16] = f2bf(hn);
          sAB[m*264 + 128 + n16] = f2bf(cn);
        }
      }
    }
    __syncthreads();  // 3

    // ---- F: o = [ct|d_new] @ l2W^T + l2b via MFMA; l3.o partials to op_s ----
    {
      f4v of = {0.f,0.f,0.f,0.f};
      #pragma unroll
      for (int kc = 0; kc < 4; ++kc){
        s8v af = *(const s8v*)((const char*)sCT + (lane&15)*272 + kc*64 + g*16);
        of = MFMA16(af, bwF[kc], of);
      }
      #pragma unroll
      for (int kc = 4; kc < 8; ++kc){
        s8v af = *(const s8v*)((const char*)sAB + (lane&15)*528 + (kc-4)*64 + g*16);
        of = MFMA16(af, bwF[kc], of);
      }
      float p0 = l3w_r*(of[0] + l2b_r);
      float p1 = l3w_r*(of[1] + l2b_r);
      float p2 = l3w_r*(of[2] + l2b_r);
      float p3 = l3w_r*(of[3] + l2b_r);
      #pragma unroll
      for (int off = 1; off <= 8; off <<= 1){
        p0 += __shfl_xor(p0, off, 64);
        p1 += __shfl_xor(p1, off, 64);
        p2 += __shfl_xor(p2, off, 64);
        p3 += __shfl_xor(p3, off, 64);
      }
      if ((lane & 15) == 0 && lane < 32){
        *(float4*)((char*)op_s + wave*32 + g*16) = make_float4(p0, p1, p2, p3);
      }
    }
    // no trailing barrier: op_s consumed after bar1+bar2 of t+1
  }
  __syncthreads();
  if (tid < 8){
    float s = 0.f;
    #pragma unroll
    for (int w = 0; w < 8; ++w) s += op_s[w][tid];
    out[bbase + tid] = fast_sig(s + l3b0);
  }
}

extern "C" void kernel_launch(void* const* d_in, const int* in_sizes, int n_in,
                              void* d_out, int out_size, void* d_ws, size_t ws_size,
                              hipStream_t stream){
  const float* X      = (const float*)d_in[0];
  const float* iaW1   = (const float*)d_in[1];
  const float* iab1   = (const float*)d_in[2];
  const float* iaW2   = (const float*)d_in[3];
  const float* encWih = (const float*)d_in[5];
  const float* encWhh = (const float*)d_in[6];
  const float* encbih = (const float*)d_in[7];
  const float* encbhh = (const float*)d_in[8];
  const float* taW1   = (const float*)d_in[9];
  const float* tab1   = (const float*)d_in[10];
  const float* taW2   = (const float*)d_in[11];
  const float* decWih = (const float*)d_in[13];
  const float* decWhh = (const float*)d_in[14];
  const float* decbih = (const float*)d_in[15];
  const float* decbhh = (const float*)d_in[16];
  const float* l1W    = (const float*)d_in[17];
  const float* l1b    = (const float*)d_in[18];
  const float* l2W    = (const float*)d_in[19];
  const float* l2b    = (const float*)d_in[20];
  const float* l3W    = (const float*)d_in[21];
  const float* l3b    = (const float*)d_in[22];

  char* ws = (char*)d_ws;
  ushort* Eenc = (ushort*)(ws);                // 32MB f16 [b][f][w]; aliased by Edec later
  ushort* Hsb  = (ushort*)(ws + 33554432);     // 32MB bf16 [b][w][h]
  ushort* HsT  = (ushort*)(ws + 2*33554432);   // 32MB bf16 [b][h][w]
  ushort* Edec = Eenc;

  k_upre<<<dim3(2048), dim3(256), 0, stream>>>(X, iaW1, Eenc);
  k_enc<<<dim3(256), dim3(512), 0, stream>>>(X, iaW1, iab1, iaW2,
                                             encWih, encWhh, encbih, encbhh,
                                             Eenc, Hsb);
  k_vpre<<<dim3(2048), dim3(256), 0, stream>>>(Hsb, taW1, Edec, HsT);
  k_dec<<<dim3(256), dim3(512), 0, stream>>>(taW1, tab1, taW2,
                                             decWih, decWhh, decbih, decbhh,
                                             l1W, l1b, l2W, l2b, l3W, l3b,
                                             Edec, HsT, (float*)d_out);
}